// Round 1
// baseline (975.855 us; speedup 1.0000x reference)
//
#include <hip/hip_runtime.h>

typedef unsigned short u16;
typedef unsigned int u32;
typedef __attribute__((ext_vector_type(8))) u16 u16x8;
typedef __attribute__((ext_vector_type(4))) float f32x4;

#define DEV static __device__ __forceinline__

DEV float bf2f(u16 u) {
  union { u32 i; float f; } v; v.i = ((u32)u) << 16; return v.f;
}
DEV u16 f2bf(float f) {
  union { float f; u32 i; } v; v.f = f;
  u32 x = v.i;
  u32 r = (x + 0x7fffu + ((x >> 16) & 1u)) >> 16;
  return (u16)r;
}

// ---------------- workspace layout (bytes) ----------------
// cost: bf16 [8][128][192][256]   = 100663296
// y1:   bf16 [8][128][64][256]    =  33554432
// y2:   bf16 [8][128][32][256]    =  16777216
// w1r:  f32  [9][192][64]         =    442368
// w2r:  f32  [9][64][32]          =     73728
// p1s/p1q: f32 [1024][64] each    =    262144 x2
// p2s/p2q: f32 [512][32]  each    =     65536 x2
// bn1:  f32 [128] (a1|bsh1)       =       512
// bn2:  f32 [64]  (a2|bsh2)       =       256
static const size_t OFF_COST = 0;
static const size_t OFF_Y1   = 100663296u;
static const size_t OFF_Y2   = 134217728u;
static const size_t OFF_W1R  = 150994944u;
static const size_t OFF_W2R  = 151437312u;
static const size_t OFF_P1S  = 151511040u;
static const size_t OFF_P1Q  = 151773184u;
static const size_t OFF_P2S  = 152035328u;
static const size_t OFF_P2Q  = 152100864u;
static const size_t OFF_BN1  = 152166400u;
static const size_t OFF_BN2  = 152166912u;

// ---------------- weight reorder ----------------
// w1r[tap][c][o] = conv1_w[o][c][kh][kw];  w2r[tap][c][o] = conv2_w[o][c][kh][kw]
__global__ void cv_prep(const float* __restrict__ w1, const float* __restrict__ w2,
                        float* __restrict__ w1r, float* __restrict__ w2r)
{
  int i = blockIdx.x * 256 + threadIdx.x;
  if (i < 110592) {
    int o = i & 63;
    int c = (i >> 6) % 192;
    int tap = i / 12288;
    int kh = tap / 3, kw = tap - kh * 3;
    w1r[i] = w1[((o * 192 + c) * 3 + kh) * 3 + kw];
  }
  if (i < 18432) {
    int o = i & 31;
    int c = (i >> 5) & 63;
    int tap = i >> 11;
    int kh = tap / 3, kw = tap - kh * 3;
    w2r[i] = w2[((o * 64 + c) * 3 + kh) * 3 + kw];
  }
}

// ---------------- cost volume ----------------
// cost[b][h][d][w] = (w>=d) ? mean_c |lf[b,c,h,w] - rf[b,c,h,w-d]| : 0   (bf16)
__global__ __launch_bounds__(256) void cv_cost(const float* __restrict__ lf,
                                               const float* __restrict__ rf,
                                               u16* __restrict__ cost)
{
  const int w = threadIdx.x;
  const int h = blockIdx.x, b = blockIdx.y;
  __shared__ float rfl[32 * 256];
  float lfr[32];
  const int base = (b * 32 * 128 + h) * 256 + w;
  #pragma unroll
  for (int c = 0; c < 32; ++c) {
    int g = base + c * (128 * 256);
    lfr[c] = lf[g];
    rfl[c * 256 + w] = rf[g];
  }
  __syncthreads();
  u16* orow = cost + ((size_t)(b * 128 + h) * 192) * 256 + w;
  for (int d = 0; d < 192; ++d) {
    int wd = w - d; wd = wd < 0 ? 0 : wd;
    float acc = 0.f;
    #pragma unroll
    for (int c = 0; c < 32; ++c) acc += fabsf(lfr[c] - rfl[c * 256 + wd]);
    u16 outv = (w >= d) ? f2bf(acc * (1.f / 32.f)) : (u16)0;
    orow[d * 256] = outv;
  }
}

// ---------------- conv1: 192->64, 3x3, pad1, + bias, + BN1 partial stats ----------------
// block = one (b,h) row, 256 threads: wo=tid&31 (8 pixels each), og=tid>>5 (8 out-ch each)
__global__ __launch_bounds__(256) void cv_conv1(
    const u16* __restrict__ cost, const float* __restrict__ w1r,
    const float* __restrict__ b1, u16* __restrict__ y1,
    float* __restrict__ p1s, float* __restrict__ p1q)
{
  __shared__ __align__(16) u16 tile[8 * 3 * 272];   // [c8][r3][272]
  __shared__ __align__(16) float wlds[9 * 8 * 64];  // [tap][c8][o64]
  __shared__ float red[128];

  const int tid = threadIdx.x;
  const int h = blockIdx.x, b = blockIdx.y;
  const int wo = tid & 31, og = tid >> 5;

  float acc[8][8];
  #pragma unroll
  for (int j = 0; j < 8; ++j)
    #pragma unroll
    for (int k = 0; k < 8; ++k) acc[j][k] = 0.f;

  if (tid < 48) {  // zero guard slots [0..8) and [264..272) of all 24 rows
    int row = tid >> 1, side = tid & 1;
    u16x8 z;
    #pragma unroll
    for (int j = 0; j < 8; ++j) z[j] = 0;
    *reinterpret_cast<u16x8*>(&tile[row * 272 + side * 264]) = z;
  }

  #pragma unroll 1
  for (int c0 = 0; c0 < 192; c0 += 8) {
    __syncthreads();
    // stage cost tile: 8c x 3r x 32 octets
    #pragma unroll 1
    for (int i = tid; i < 768; i += 256) {
      int kk = i & 31;
      int rest = i >> 5;            // 0..23
      int r = rest % 3, cc = rest / 3;
      int hp = h + r - 1;
      u16x8 val;
      #pragma unroll
      for (int j = 0; j < 8; ++j) val[j] = 0;
      if (hp >= 0 && hp < 128) {
        val = *reinterpret_cast<const u16x8*>(
            cost + ((size_t)((b * 128 + hp) * 192 + c0 + cc)) * 256 + kk * 8);
      }
      *reinterpret_cast<u16x8*>(&tile[(cc * 3 + r) * 272 + 8 + kk * 8]) = val;
    }
    // stage weights: 9 taps x 8c x 64o = 1152 float4
    #pragma unroll 1
    for (int i = tid; i < 1152; i += 256) {
      int tap = i >> 7;
      int rest = i & 127;
      f32x4 v = *reinterpret_cast<const f32x4*>(w1r + (tap * 192 + c0) * 64 + rest * 4);
      *reinterpret_cast<f32x4*>(&wlds[tap * 512 + rest * 4]) = v;
    }
    __syncthreads();

    #pragma unroll 1
    for (int cc = 0; cc < 8; ++cc) {
      #pragma unroll
      for (int kh = 0; kh < 3; ++kh) {
        const u16* trow = &tile[(cc * 3 + kh) * 272 + 8 + wo * 8];
        float v[10];
        u16x8 m = *reinterpret_cast<const u16x8*>(trow);
        v[0] = bf2f(trow[-1]);
        #pragma unroll
        for (int j = 0; j < 8; ++j) v[1 + j] = bf2f(m[j]);
        v[9] = bf2f(trow[8]);
        float wv[3][8];
        #pragma unroll
        for (int kw = 0; kw < 3; ++kw)
          #pragma unroll
          for (int k = 0; k < 8; ++k)
            wv[kw][k] = wlds[((kh * 3 + kw) * 8 + cc) * 64 + og * 8 + k];
        #pragma unroll
        for (int kw = 0; kw < 3; ++kw)
          #pragma unroll
          for (int j = 0; j < 8; ++j)
            #pragma unroll
            for (int k = 0; k < 8; ++k)
              acc[j][k] = fmaf(v[j + kw], wv[kw][k], acc[j][k]);
      }
    }
  }

  #pragma unroll
  for (int k = 0; k < 8; ++k) {
    float bias = b1[og * 8 + k];
    #pragma unroll
    for (int j = 0; j < 8; ++j) acc[j][k] += bias;
  }

  // store y1 [b][h][o][w] bf16, coalesced 16B runs
  #pragma unroll
  for (int k = 0; k < 8; ++k) {
    u16x8 pk;
    #pragma unroll
    for (int j = 0; j < 8; ++j) pk[j] = f2bf(acc[j][k]);
    *reinterpret_cast<u16x8*>(
        y1 + ((size_t)((b * 128 + h) * 64 + og * 8 + k)) * 256 + wo * 8) = pk;
  }

  // BN1 partial stats (deterministic)
  float s[8], q[8];
  #pragma unroll
  for (int k = 0; k < 8; ++k) {
    s[k] = 0.f; q[k] = 0.f;
    #pragma unroll
    for (int j = 0; j < 8; ++j) { s[k] += acc[j][k]; q[k] += acc[j][k] * acc[j][k]; }
  }
  #pragma unroll
  for (int mm = 1; mm < 32; mm <<= 1) {
    #pragma unroll
    for (int k = 0; k < 8; ++k) {
      s[k] += __shfl_xor(s[k], mm, 64);
      q[k] += __shfl_xor(q[k], mm, 64);
    }
  }
  if ((tid & 31) == 0) {
    #pragma unroll
    for (int k = 0; k < 8; ++k) { red[og * 8 + k] = s[k]; red[64 + og * 8 + k] = q[k]; }
  }
  __syncthreads();
  if (tid < 64) {
    int bidx = b * 128 + h;
    p1s[bidx * 64 + tid] = red[tid];
    p1q[bidx * 64 + tid] = red[64 + tid];
  }
}

// ---------------- finalize BN stats ----------------
__global__ void cv_fin1(const float* __restrict__ p1s, const float* __restrict__ p1q,
                        const float* __restrict__ g, const float* __restrict__ be,
                        float* __restrict__ bn1)
{
  int o = threadIdx.x;
  if (o >= 64) return;
  float s = 0.f, q = 0.f;
  #pragma unroll 4
  for (int k = 0; k < 1024; ++k) { s += p1s[k * 64 + o]; q += p1q[k * 64 + o]; }
  float inv = 1.f / 262144.f;
  float mean = s * inv;
  float var = q * inv - mean * mean;
  float a = g[o] * rsqrtf(var + 1e-5f);
  bn1[o] = a;
  bn1[64 + o] = be[o] - mean * a;
}

__global__ void cv_fin2(const float* __restrict__ p2s, const float* __restrict__ p2q,
                        const float* __restrict__ g, const float* __restrict__ be,
                        float* __restrict__ bn2)
{
  int o = threadIdx.x;
  if (o >= 32) return;
  float s = 0.f, q = 0.f;
  #pragma unroll 4
  for (int k = 0; k < 512; ++k) { s += p2s[k * 32 + o]; q += p2q[k * 32 + o]; }
  float inv = 1.f / 262144.f;
  float mean = s * inv;
  float var = q * inv - mean * mean;
  float a = g[o] * rsqrtf(var + 1e-5f);
  bn2[o] = a;
  bn2[32 + o] = be[o] - mean * a;
}

// ---------------- conv2: 64->32, 3x3, pad1; input = relu(bn1(y1)) applied at staging ----------------
// block covers 2 rows x 256 w; wo=tid&31, og=(tid>>5)&3, rr=tid>>7
__global__ __launch_bounds__(256) void cv_conv2(
    const u16* __restrict__ y1, const float* __restrict__ w2r,
    const float* __restrict__ b2, const float* __restrict__ bn1,
    u16* __restrict__ y2, float* __restrict__ p2s, float* __restrict__ p2q)
{
  __shared__ __align__(16) u16 tile[8 * 4 * 272];   // [c8][r4][272]
  __shared__ __align__(16) float wlds[9 * 8 * 32];  // [tap][c8][o32]
  __shared__ float red[128];

  const int tid = threadIdx.x;
  const int h0 = blockIdx.x * 2, b = blockIdx.y;
  const int wo = tid & 31, og = (tid >> 5) & 3, rr = tid >> 7;

  float acc[8][8];
  #pragma unroll
  for (int j = 0; j < 8; ++j)
    #pragma unroll
    for (int k = 0; k < 8; ++k) acc[j][k] = 0.f;

  if (tid < 64) {  // zero guard slots of 32 rows
    int row = tid >> 1, side = tid & 1;
    u16x8 z;
    #pragma unroll
    for (int j = 0; j < 8; ++j) z[j] = 0;
    *reinterpret_cast<u16x8*>(&tile[row * 272 + side * 264]) = z;
  }

  #pragma unroll 1
  for (int c0 = 0; c0 < 64; c0 += 8) {
    __syncthreads();
    #pragma unroll 1
    for (int i = tid; i < 1024; i += 256) {
      int kk = i & 31, r = (i >> 5) & 3, cc = i >> 7;
      int hp = h0 + r - 1;
      u16x8 val;
      #pragma unroll
      for (int j = 0; j < 8; ++j) val[j] = 0;
      if (hp >= 0 && hp < 128) {
        u16x8 raw = *reinterpret_cast<const u16x8*>(
            y1 + ((size_t)((b * 128 + hp) * 64 + c0 + cc)) * 256 + kk * 8);
        float a = bn1[c0 + cc], bb = bn1[64 + c0 + cc];
        #pragma unroll
        for (int j = 0; j < 8; ++j) {
          float f = fmaf(bf2f(raw[j]), a, bb);
          f = fmaxf(f, 0.f);
          val[j] = f2bf(f);
        }
      }
      *reinterpret_cast<u16x8*>(&tile[(cc * 4 + r) * 272 + 8 + kk * 8]) = val;
    }
    #pragma unroll 1
    for (int i = tid; i < 576; i += 256) {
      int tap = i >> 6;
      int rest = i & 63;
      f32x4 v = *reinterpret_cast<const f32x4*>(w2r + (tap * 64 + c0) * 32 + rest * 4);
      *reinterpret_cast<f32x4*>(&wlds[tap * 256 + rest * 4]) = v;
    }
    __syncthreads();

    #pragma unroll 1
    for (int cc = 0; cc < 8; ++cc) {
      #pragma unroll
      for (int kh = 0; kh < 3; ++kh) {
        const u16* trow = &tile[(cc * 4 + rr + kh) * 272 + 8 + wo * 8];
        float v[10];
        u16x8 m = *reinterpret_cast<const u16x8*>(trow);
        v[0] = bf2f(trow[-1]);
        #pragma unroll
        for (int j = 0; j < 8; ++j) v[1 + j] = bf2f(m[j]);
        v[9] = bf2f(trow[8]);
        float wv[3][8];
        #pragma unroll
        for (int kw = 0; kw < 3; ++kw)
          #pragma unroll
          for (int k = 0; k < 8; ++k)
            wv[kw][k] = wlds[((kh * 3 + kw) * 8 + cc) * 32 + og * 8 + k];
        #pragma unroll
        for (int kw = 0; kw < 3; ++kw)
          #pragma unroll
          for (int j = 0; j < 8; ++j)
            #pragma unroll
            for (int k = 0; k < 8; ++k)
              acc[j][k] = fmaf(v[j + kw], wv[kw][k], acc[j][k]);
      }
    }
  }

  #pragma unroll
  for (int k = 0; k < 8; ++k) {
    float bias = b2[og * 8 + k];
    #pragma unroll
    for (int j = 0; j < 8; ++j) acc[j][k] += bias;
  }

  #pragma unroll
  for (int k = 0; k < 8; ++k) {
    u16x8 pk;
    #pragma unroll
    for (int j = 0; j < 8; ++j) pk[j] = f2bf(acc[j][k]);
    *reinterpret_cast<u16x8*>(
        y2 + ((size_t)((b * 128 + h0 + rr) * 32 + og * 8 + k)) * 256 + wo * 8) = pk;
  }

  float s[8], q[8];
  #pragma unroll
  for (int k = 0; k < 8; ++k) {
    s[k] = 0.f; q[k] = 0.f;
    #pragma unroll
    for (int j = 0; j < 8; ++j) { s[k] += acc[j][k]; q[k] += acc[j][k] * acc[j][k]; }
  }
  #pragma unroll
  for (int mm = 1; mm < 32; mm <<= 1) {
    #pragma unroll
    for (int k = 0; k < 8; ++k) {
      s[k] += __shfl_xor(s[k], mm, 64);
      q[k] += __shfl_xor(q[k], mm, 64);
    }
  }
  if ((tid & 31) == 0) {
    int gix = rr * 4 + og;
    #pragma unroll
    for (int k = 0; k < 8; ++k) { red[gix * 8 + k] = s[k]; red[64 + gix * 8 + k] = q[k]; }
  }
  __syncthreads();
  if (tid < 32) {
    int bidx = b * 64 + blockIdx.x;
    p2s[bidx * 32 + tid] = red[tid] + red[32 + tid];
    p2q[bidx * 32 + tid] = red[64 + tid] + red[96 + tid];
  }
}

// ---------------- deconv: ConvTranspose2d(32,1,4,2,1); input = relu(bn2(y2)) ----------------
__global__ __launch_bounds__(256) void cv_deconv(
    const u16* __restrict__ y2, const float* __restrict__ bn2,
    const float* __restrict__ wd, const float* __restrict__ db,
    float* __restrict__ out)
{
  const int tid = threadIdx.x;
  const int blk = blockIdx.x;
  const int b = blk >> 9;
  const int oh = (blk >> 1) & 255;
  const int ow = (blk & 1) * 256 + tid;
  float acc = db[0];
  const int qp = (oh + 1) & 1;
  const int rp = (ow + 1) & 1;
  #pragma unroll
  for (int t = 0; t < 2; ++t) {
    int kh = qp + 2 * t;
    int ih = (oh + 1 - kh) >> 1;
    if (ih < 0 || ih >= 128) continue;
    #pragma unroll
    for (int u = 0; u < 2; ++u) {
      int kw = rp + 2 * u;
      int iw = (ow + 1 - kw) >> 1;
      if (iw < 0 || iw >= 256) continue;
      const u16* base = y2 + ((size_t)(b * 128 + ih) * 32) * 256 + iw;
      #pragma unroll
      for (int c = 0; c < 32; ++c) {
        float v = bf2f(base[c * 256]);
        float x = fmaxf(fmaf(v, bn2[c], bn2[32 + c]), 0.f);
        acc = fmaf(x, wd[c * 16 + kh * 4 + kw], acc);
      }
    }
  }
  out[(size_t)(b * 256 + oh) * 512 + ow] = acc;
}

// ---------------- launcher ----------------
extern "C" void kernel_launch(void* const* d_in, const int* in_sizes, int n_in,
                              void* d_out, int out_size, void* d_ws, size_t ws_size,
                              hipStream_t stream)
{
  const float* lf  = (const float*)d_in[0];
  const float* rf  = (const float*)d_in[1];
  const float* w1  = (const float*)d_in[2];
  const float* b1  = (const float*)d_in[3];
  const float* g1  = (const float*)d_in[4];
  const float* be1 = (const float*)d_in[5];
  const float* w2  = (const float*)d_in[6];
  const float* b2  = (const float*)d_in[7];
  const float* g2  = (const float*)d_in[8];
  const float* be2 = (const float*)d_in[9];
  const float* wdc = (const float*)d_in[10];
  const float* dbc = (const float*)d_in[11];
  float* out = (float*)d_out;

  char* ws = (char*)d_ws;
  u16* cost  = (u16*)(ws + OFF_COST);
  u16* y1    = (u16*)(ws + OFF_Y1);
  u16* y2    = (u16*)(ws + OFF_Y2);
  float* w1r = (float*)(ws + OFF_W1R);
  float* w2r = (float*)(ws + OFF_W2R);
  float* p1s = (float*)(ws + OFF_P1S);
  float* p1q = (float*)(ws + OFF_P1Q);
  float* p2s = (float*)(ws + OFF_P2S);
  float* p2q = (float*)(ws + OFF_P2Q);
  float* bn1 = (float*)(ws + OFF_BN1);
  float* bn2 = (float*)(ws + OFF_BN2);

  cv_prep<<<dim3(432), dim3(256), 0, stream>>>(w1, w2, w1r, w2r);
  cv_cost<<<dim3(128, 8), dim3(256), 0, stream>>>(lf, rf, cost);
  cv_conv1<<<dim3(128, 8), dim3(256), 0, stream>>>(cost, w1r, b1, y1, p1s, p1q);
  cv_fin1<<<dim3(1), dim3(64), 0, stream>>>(p1s, p1q, g1, be1, bn1);
  cv_conv2<<<dim3(64, 8), dim3(256), 0, stream>>>(y1, w2r, b2, bn1, y2, p2s, p2q);
  cv_fin2<<<dim3(1), dim3(64), 0, stream>>>(p2s, p2q, g2, be2, bn2);
  cv_deconv<<<dim3(4096), dim3(256), 0, stream>>>(y2, bn2, wdc, dbc, out);
}

// Round 2
// 508.644 us; speedup vs baseline: 1.9185x; 1.9185x over previous
//
#include <hip/hip_runtime.h>

typedef unsigned short u16;
typedef unsigned int u32;
typedef __attribute__((ext_vector_type(8))) u16 u16x8;
typedef __attribute__((ext_vector_type(4))) float f32x4;
typedef __attribute__((ext_vector_type(8))) _Float16 h8;

#define DEV static __device__ __forceinline__

DEV u16 f2h(float f) {
  union { _Float16 h; u16 u; } v; v.h = (_Float16)f; return v.u;
}
DEV float h2f(u16 u) {
  union { u16 u; _Float16 h; } v; v.u = u; return (float)v.h;
}

DEV void gl_lds16(const void* g, void* l) {
  __builtin_amdgcn_global_load_lds(
      (const __attribute__((address_space(1))) unsigned int*)g,
      (__attribute__((address_space(3))) unsigned int*)l,
      16, 0, 0);
}

// ---------------- workspace layout (bytes) ----------------
// cost: f16 [8][128][12][256][16] = 100,663,296
// y1:   f16 [8][128][4][256][16]  =  33,554,432   (overwritten in place by relu(bn1(.)))
// y2:   f16 [8][128][2][256][16]  =  16,777,216
// w1s:  f16 [12][5][64][32]       =     245,760
// w2s:  f16 [4][5][32][32]        =      40,960
// p1s/p1q: f32 [512][64]          =     131,072 x2
// p2s/p2q: f32 [512][32]          =      65,536 x2
// bn1: f32[128]  bn2: f32[64]
static const size_t OFF_COST = 0;
static const size_t OFF_Y1   = 100663296u;
static const size_t OFF_Y2   = 134217728u;
static const size_t OFF_W1S  = 150994944u;
static const size_t OFF_W2S  = 151240704u;
static const size_t OFF_P1S  = 151281664u;
static const size_t OFF_P1Q  = 151412736u;
static const size_t OFF_P2S  = 151543808u;
static const size_t OFF_P2Q  = 151609344u;
static const size_t OFF_BN1  = 151674880u;
static const size_t OFF_BN2  = 151675392u;

// ---------------- weight reorder + f16 convert ----------------
// w1s[cg][s][o][k], k = slot*16+dc, tap = 2s+slot; tap 9 = zero pad.
__global__ void cv_prep(const float* __restrict__ w1, const float* __restrict__ w2,
                        u16* __restrict__ w1s, u16* __restrict__ w2s)
{
  int i = blockIdx.x * 256 + threadIdx.x;
  if (i < 122880) {
    int k = i & 31, o = (i >> 5) & 63;
    int s = (i >> 11) % 5, cg = (i >> 11) / 5;
    int slot = k >> 4, dc = k & 15;
    int tap = 2 * s + slot;
    float v = 0.f;
    if (tap < 9) {
      int kh = tap / 3, kw = tap % 3;
      int c = cg * 16 + dc;
      v = w1[((o * 192 + c) * 3 + kh) * 3 + kw];
    }
    w1s[i] = f2h(v);
  }
  if (i < 20480) {
    int k = i & 31, o = (i >> 5) & 31;
    int s = (i >> 10) % 5, cg = (i >> 10) / 5;
    int slot = k >> 4, dc = k & 15;
    int tap = 2 * s + slot;
    float v = 0.f;
    if (tap < 9) {
      int kh = tap / 3, kw = tap % 3;
      int c = cg * 16 + dc;
      v = w2[((o * 64 + c) * 3 + kh) * 3 + kw];
    }
    w2s[i] = f2h(v);
  }
}

// ---------------- cost volume ----------------
// cost[b][h][cg][w][dc] = (w>=d) ? mean_c |lf - rf shifted| : 0, d = cg*16+dc (f16)
__global__ __launch_bounds__(256) void cv_cost(const float* __restrict__ lf,
                                               const float* __restrict__ rf,
                                               u16* __restrict__ cost)
{
  const int w = threadIdx.x;
  const int h = blockIdx.x, b = blockIdx.y;
  __shared__ float rfl[32 * 256];
  float lfr[32];
  const int base = (b * 32 * 128 + h) * 256 + w;
  #pragma unroll
  for (int c = 0; c < 32; ++c) {
    int g = base + c * (128 * 256);
    lfr[c] = lf[g];
    rfl[c * 256 + w] = rf[g];
  }
  __syncthreads();
  u16* orow = cost + (((size_t)(b * 128 + h)) * 12) * 4096 + w * 16;
  #pragma unroll 1
  for (int cg = 0; cg < 12; ++cg) {
    u16x8 lo, hi;
    #pragma unroll
    for (int dc = 0; dc < 16; ++dc) {
      int d = cg * 16 + dc;
      int wd = w - d; wd = wd < 0 ? 0 : wd;
      float acc = 0.f;
      #pragma unroll
      for (int c = 0; c < 32; ++c) acc += fabsf(lfr[c] - rfl[c * 256 + wd]);
      u16 v = (w >= d) ? f2h(acc * (1.f / 32.f)) : (u16)0;
      if (dc < 8) lo[dc] = v; else hi[dc - 8] = v;
    }
    *reinterpret_cast<u16x8*>(orow + cg * 4096) = lo;
    *reinterpret_cast<u16x8*>(orow + cg * 4096 + 8) = hi;
  }
}

// ---------------- MFMA implicit-GEMM 3x3 conv ----------------
// act: [8][128][NCG][256][16] f16; wre: [NCG][5][OC][32] f16 (tap-pair packed)
// block: 4 waves, rows {h0,h0+1} x 256 w; wave = (row, half): 128 px x OC
// Per wave: 8 M-frags x (OC/16) N-frags of mfma_f32_16x16x32_f16.
template<int OC>
__global__ __launch_bounds__(256) void cv_convm(
    const u16* __restrict__ act, const u16* __restrict__ wre,
    const float* __restrict__ bias, u16* __restrict__ yout,
    float* __restrict__ ps, float* __restrict__ pq, int NCG)
{
  constexpr int NF = OC / 16;
  constexpr int NWCH = (5 * OC * 32 * 2) / 1024;  // 1KB weight chunks per cg

  __shared__ __align__(16) u16 at[4 * 258 * 16];   // 33,024 B
  __shared__ __align__(16) u16 wl[5 * 64 * 32];    // 20,480 B (OC=32 uses half)
  __shared__ float reds[4][64];
  __shared__ float redq[4][64];

  const int tid = threadIdx.x;
  const int rp = blockIdx.x, b = blockIdx.y;
  const int h0 = rp * 2;
  const int q = tid >> 6, lane = tid & 63;
  const int lanelo = lane & 15, lanehi = lane >> 4;
  const int selB = lane >> 5;            // tap slot within K-step
  const int dcb = (lanehi & 1) * 8;      // dc sub-offset
  const int r = q >> 1, hf = q & 1;      // wave row / half
  const int wbase = hf * 128 + lanelo;

  // init: zero halo columns (w=0 and w=257 of each tile row)
  if (tid < 128) {
    int tr = tid >> 5, side = (tid >> 4) & 1, dc = tid & 15;
    at[(tr * 258 + side * 257) * 16 + dc] = 0;
  }
  // zero out-of-range rows (only possible at image top/bottom)
  if (h0 == 0)   for (int i = tid; i < 258 * 16; i += 256) at[i] = 0;
  if (h0 == 126) for (int i = tid; i < 258 * 16; i += 256) at[3 * 258 * 16 + i] = 0;

  f32x4 acc[8][NF];
  #pragma unroll
  for (int mf = 0; mf < 8; ++mf)
    #pragma unroll
    for (int nf = 0; nf < NF; ++nf)
      acc[mf][nf] = (f32x4){0.f, 0.f, 0.f, 0.f};

  const int hsrc = h0 - 1 + q;
  const bool rowok = (hsrc >= 0) && (hsrc < 128);

  #pragma unroll 1
  for (int cg = 0; cg < NCG; ++cg) {
    // ---- stage A: wave q -> tile row q (8 KB linear) ----
    if (rowok) {
      const u16* src = act + ((size_t)((b * 128 + hsrc) * NCG + cg)) * 4096;
      u16* dst = &at[(q * 258 + 1) * 16];
      #pragma unroll
      for (int i = 0; i < 8; ++i)
        gl_lds16(src + i * 512 + lane * 8, dst + i * 512);
    }
    // ---- stage W ----
    {
      const u16* wsrc = wre + (size_t)cg * (5 * OC * 32);
      for (int ch = q; ch < NWCH; ch += 4)
        gl_lds16(wsrc + ch * 512 + lane * 8, &wl[ch * 512]);
    }
    __syncthreads();

    // ---- compute: 5 K-steps of 32 (tap-pair x 16 ch) ----
    #pragma unroll
    for (int s = 0; s < 5; ++s) {
      const int tA = 2 * s, tB = (2 * s + 1 < 9) ? (2 * s + 1) : 8;
      const int khA = tA / 3, kwA = tA % 3;
      const int khB = tB / 3, kwB = tB % 3;
      const int kh = selB ? khB : khA;
      const int kw = selB ? kwB : kwA;
      h8 bfr[NF];
      #pragma unroll
      for (int nf = 0; nf < NF; ++nf)
        bfr[nf] = *reinterpret_cast<const h8*>(&wl[(s * OC + nf * 16 + lanelo) * 32 + lanehi * 8]);
      const int abase = ((r + kh) * 258 + wbase + kw) * 16 + dcb;
      #pragma unroll
      for (int mf = 0; mf < 8; ++mf) {
        h8 a = *reinterpret_cast<const h8*>(&at[abase + mf * 256]);
        #pragma unroll
        for (int nf = 0; nf < NF; ++nf)
          acc[mf][nf] = __builtin_amdgcn_mfma_f32_16x16x32_f16(a, bfr[nf], acc[mf][nf], 0, 0, 0);
      }
    }
    __syncthreads();  // protect LDS before next-stage overwrite
  }

  // ---- epilogue: bias, BN partial stats, transposed store ----
  #pragma unroll
  for (int nf = 0; nf < NF; ++nf) {
    float bv = bias[nf * 16 + lanelo];
    #pragma unroll
    for (int mf = 0; mf < 8; ++mf)
      #pragma unroll
      for (int e = 0; e < 4; ++e)
        acc[mf][nf][e] += bv;
  }

  float s_[NF], qq[NF];
  #pragma unroll
  for (int nf = 0; nf < NF; ++nf) {
    s_[nf] = 0.f; qq[nf] = 0.f;
    #pragma unroll
    for (int mf = 0; mf < 8; ++mf)
      #pragma unroll
      for (int e = 0; e < 4; ++e) {
        float v = acc[mf][nf][e];
        s_[nf] += v; qq[nf] += v * v;
      }
  }
  #pragma unroll
  for (int nf = 0; nf < NF; ++nf) {
    s_[nf] += __shfl_xor(s_[nf], 16, 64);
    s_[nf] += __shfl_xor(s_[nf], 32, 64);
    qq[nf] += __shfl_xor(qq[nf], 16, 64);
    qq[nf] += __shfl_xor(qq[nf], 32, 64);
  }
  if (lanehi == 0) {
    #pragma unroll
    for (int nf = 0; nf < NF; ++nf) {
      reds[q][nf * 16 + lanelo] = s_[nf];
      redq[q][nf * 16 + lanelo] = qq[nf];
    }
  }
  __syncthreads();
  if (tid < OC) {
    int bid = b * 64 + rp;
    ps[bid * OC + tid] = reds[0][tid] + reds[1][tid] + reds[2][tid] + reds[3][tid];
    pq[bid * OC + tid] = redq[0][tid] + redq[1][tid] + redq[2][tid] + redq[3][tid];
  }

  u16* eb = at;  // reuse A-tile region: [512 px][16 o]
  #pragma unroll 1
  for (int nf = 0; nf < NF; ++nf) {
    __syncthreads();
    #pragma unroll
    for (int mf = 0; mf < 8; ++mf)
      #pragma unroll
      for (int e = 0; e < 4; ++e) {
        int px = r * 256 + hf * 128 + mf * 16 + lanehi * 4 + e;
        eb[px * 16 + lanelo] = f2h(acc[mf][nf][e]);
      }
    __syncthreads();
    #pragma unroll
    for (int j = 0; j < 4; ++j) {
      int c = j * 256 + tid;           // 1024 chunks of 8 u16
      int row = c >> 9, off = (c & 511) * 8;
      u16x8 v = *reinterpret_cast<const u16x8*>(&eb[c * 8]);
      *reinterpret_cast<u16x8*>(
          yout + ((size_t)((b * 128 + h0 + row) * NF + nf)) * 4096 + off) = v;
    }
  }
}

// ---------------- finalize BN stats ----------------
__global__ void cv_fin1(const float* __restrict__ p1s, const float* __restrict__ p1q,
                        const float* __restrict__ g, const float* __restrict__ be,
                        float* __restrict__ bn1)
{
  int o = threadIdx.x;
  if (o >= 64) return;
  float s = 0.f, q = 0.f;
  #pragma unroll 4
  for (int k = 0; k < 512; ++k) { s += p1s[k * 64 + o]; q += p1q[k * 64 + o]; }
  float inv = 1.f / 262144.f;
  float mean = s * inv;
  float var = q * inv - mean * mean;
  float a = g[o] * rsqrtf(var + 1e-5f);
  bn1[o] = a;
  bn1[64 + o] = be[o] - mean * a;
}

__global__ void cv_fin2(const float* __restrict__ p2s, const float* __restrict__ p2q,
                        const float* __restrict__ g, const float* __restrict__ be,
                        float* __restrict__ bn2)
{
  int o = threadIdx.x;
  if (o >= 32) return;
  float s = 0.f, q = 0.f;
  #pragma unroll 4
  for (int k = 0; k < 512; ++k) { s += p2s[k * 32 + o]; q += p2q[k * 32 + o]; }
  float inv = 1.f / 262144.f;
  float mean = s * inv;
  float var = q * inv - mean * mean;
  float a = g[o] * rsqrtf(var + 1e-5f);
  bn2[o] = a;
  bn2[32 + o] = be[o] - mean * a;
}

// ---------------- y1 <- relu(bn1(y1)) in place ----------------
__global__ __launch_bounds__(256) void cv_bnrelu1(u16* __restrict__ y1,
                                                  const float* __restrict__ bn1)
{
  size_t i = ((size_t)blockIdx.x * 256 + threadIdx.x) * 8;
  int dc0 = (int)(i & 15);            // 0 or 8
  int cg = (int)((i >> 12) & 3);
  int o0 = cg * 16 + dc0;
  f32x4 a0 = *reinterpret_cast<const f32x4*>(&bn1[o0]);
  f32x4 a1 = *reinterpret_cast<const f32x4*>(&bn1[o0 + 4]);
  f32x4 s0 = *reinterpret_cast<const f32x4*>(&bn1[64 + o0]);
  f32x4 s1 = *reinterpret_cast<const f32x4*>(&bn1[64 + o0 + 4]);
  u16x8 v = *reinterpret_cast<const u16x8*>(&y1[i]);
  u16x8 outv;
  #pragma unroll
  for (int j = 0; j < 8; ++j) {
    float aj = (j < 4) ? a0[j] : a1[j - 4];
    float sj = (j < 4) ? s0[j] : s1[j - 4];
    float f = fmaxf(fmaf(h2f(v[j]), aj, sj), 0.f);
    outv[j] = f2h(f);
  }
  *reinterpret_cast<u16x8*>(&y1[i]) = outv;
}

// ---------------- deconv: ConvTranspose2d(32,1,4,2,1); input = relu(bn2(y2)) ----------------
__global__ __launch_bounds__(256) void cv_deconv(
    const u16* __restrict__ y2, const float* __restrict__ bn2,
    const float* __restrict__ wd, const float* __restrict__ db,
    float* __restrict__ out)
{
  const int tid = threadIdx.x;
  const int blk = blockIdx.x;
  const int b = blk >> 9;
  const int oh = (blk >> 1) & 255;
  const int ow = (blk & 1) * 256 + tid;
  float acc = db[0];
  const int qp = (oh + 1) & 1;
  const int rp = (ow + 1) & 1;
  #pragma unroll
  for (int t = 0; t < 2; ++t) {
    int kh = qp + 2 * t;
    int ih = (oh + 1 - kh) >> 1;
    if (ih < 0 || ih >= 128) continue;
    #pragma unroll
    for (int u = 0; u < 2; ++u) {
      int kw = rp + 2 * u;
      int iw = (ow + 1 - kw) >> 1;
      if (iw < 0 || iw >= 256) continue;
      const u16* base = y2 + (size_t)(b * 128 + ih) * 8192 + iw * 16;
      #pragma unroll
      for (int c = 0; c < 32; ++c) {
        float v = h2f(base[(c >> 4) * 4096 + (c & 15)]);
        float x = fmaxf(fmaf(v, bn2[c], bn2[32 + c]), 0.f);
        acc = fmaf(x, wd[c * 16 + kh * 4 + kw], acc);
      }
    }
  }
  out[(size_t)(b * 256 + oh) * 512 + ow] = acc;
}

// ---------------- launcher ----------------
extern "C" void kernel_launch(void* const* d_in, const int* in_sizes, int n_in,
                              void* d_out, int out_size, void* d_ws, size_t ws_size,
                              hipStream_t stream)
{
  const float* lf  = (const float*)d_in[0];
  const float* rf  = (const float*)d_in[1];
  const float* w1  = (const float*)d_in[2];
  const float* b1  = (const float*)d_in[3];
  const float* g1  = (const float*)d_in[4];
  const float* be1 = (const float*)d_in[5];
  const float* w2  = (const float*)d_in[6];
  const float* b2  = (const float*)d_in[7];
  const float* g2  = (const float*)d_in[8];
  const float* be2 = (const float*)d_in[9];
  const float* wdc = (const float*)d_in[10];
  const float* dbc = (const float*)d_in[11];
  float* out = (float*)d_out;

  char* ws = (char*)d_ws;
  u16* cost  = (u16*)(ws + OFF_COST);
  u16* y1    = (u16*)(ws + OFF_Y1);
  u16* y2    = (u16*)(ws + OFF_Y2);
  u16* w1s   = (u16*)(ws + OFF_W1S);
  u16* w2s   = (u16*)(ws + OFF_W2S);
  float* p1s = (float*)(ws + OFF_P1S);
  float* p1q = (float*)(ws + OFF_P1Q);
  float* p2s = (float*)(ws + OFF_P2S);
  float* p2q = (float*)(ws + OFF_P2Q);
  float* bn1 = (float*)(ws + OFF_BN1);
  float* bn2 = (float*)(ws + OFF_BN2);

  cv_prep<<<dim3(480), dim3(256), 0, stream>>>(w1, w2, w1s, w2s);
  cv_cost<<<dim3(128, 8), dim3(256), 0, stream>>>(lf, rf, cost);
  cv_convm<64><<<dim3(64, 8), dim3(256), 0, stream>>>(cost, w1s, b1, y1, p1s, p1q, 12);
  cv_fin1<<<dim3(1), dim3(64), 0, stream>>>(p1s, p1q, g1, be1, bn1);
  cv_bnrelu1<<<dim3(8192), dim3(256), 0, stream>>>(y1, bn1);
  cv_convm<32><<<dim3(64, 8), dim3(256), 0, stream>>>(y1, w2s, b2, y2, p2s, p2q, 4);
  cv_fin2<<<dim3(1), dim3(64), 0, stream>>>(p2s, p2q, g2, be2, bn2);
  cv_deconv<<<dim3(4096), dim3(256), 0, stream>>>(y2, bn2, wdc, dbc, out);
}

// Round 3
// 356.489 us; speedup vs baseline: 2.7374x; 1.4268x over previous
//
#include <hip/hip_runtime.h>

typedef unsigned short u16;
typedef unsigned int u32;
typedef __attribute__((ext_vector_type(8))) u16 u16x8;
typedef __attribute__((ext_vector_type(4))) float f32x4;
typedef __attribute__((ext_vector_type(8))) _Float16 h8;

#define DEV static __device__ __forceinline__

DEV u16 f2h(float f) {
  union { _Float16 h; u16 u; } v; v.h = (_Float16)f; return v.u;
}
DEV float h2f(u16 u) {
  union { u16 u; _Float16 h; } v; v.u = u; return (float)v.h;
}

DEV void gl_lds16(const void* g, void* l) {
  __builtin_amdgcn_global_load_lds(
      (const __attribute__((address_space(1))) unsigned int*)g,
      (__attribute__((address_space(3))) unsigned int*)l,
      16, 0, 0);
}

// ---------------- workspace layout (bytes) ----------------
static const size_t OFF_COST = 0;
static const size_t OFF_Y1   = 100663296u;
static const size_t OFF_Y2   = 134217728u;
static const size_t OFF_W1S  = 150994944u;
static const size_t OFF_W2S  = 151240704u;
static const size_t OFF_P1S  = 151281664u;
static const size_t OFF_P1Q  = 151412736u;
static const size_t OFF_P2S  = 151543808u;
static const size_t OFF_P2Q  = 151609344u;
static const size_t OFF_BN1  = 151674880u;
static const size_t OFF_BN2  = 151675392u;

// ---------------- weight reorder + f16 convert ----------------
__global__ void cv_prep(const float* __restrict__ w1, const float* __restrict__ w2,
                        u16* __restrict__ w1s, u16* __restrict__ w2s)
{
  int i = blockIdx.x * 256 + threadIdx.x;
  if (i < 122880) {
    int k = i & 31, o = (i >> 5) & 63;
    int s = (i >> 11) % 5, cg = (i >> 11) / 5;
    int slot = k >> 4, dc = k & 15;
    int tap = 2 * s + slot;
    float v = 0.f;
    if (tap < 9) {
      int kh = tap / 3, kw = tap % 3;
      int c = cg * 16 + dc;
      v = w1[((o * 192 + c) * 3 + kh) * 3 + kw];
    }
    w1s[i] = f2h(v);
  }
  if (i < 20480) {
    int k = i & 31, o = (i >> 5) & 31;
    int s = (i >> 10) % 5, cg = (i >> 10) / 5;
    int slot = k >> 4, dc = k & 15;
    int tap = 2 * s + slot;
    float v = 0.f;
    if (tap < 9) {
      int kh = tap / 3, kw = tap % 3;
      int c = cg * 16 + dc;
      v = w2[((o * 64 + c) * 3 + kh) * 3 + kw];
    }
    w2s[i] = f2h(v);
  }
}

// ---------------- cost volume ----------------
__global__ __launch_bounds__(256) void cv_cost(const float* __restrict__ lf,
                                               const float* __restrict__ rf,
                                               u16* __restrict__ cost)
{
  const int w = threadIdx.x;
  const int h = blockIdx.x, b = blockIdx.y;
  __shared__ float rfl[32 * 256];
  float lfr[32];
  const int base = (b * 32 * 128 + h) * 256 + w;
  #pragma unroll
  for (int c = 0; c < 32; ++c) {
    int g = base + c * (128 * 256);
    lfr[c] = lf[g];
    rfl[c * 256 + w] = rf[g];
  }
  __syncthreads();
  u16* orow = cost + (((size_t)(b * 128 + h)) * 12) * 4096 + w * 16;
  #pragma unroll 1
  for (int cg = 0; cg < 12; ++cg) {
    u16x8 lo, hi;
    #pragma unroll
    for (int dc = 0; dc < 16; ++dc) {
      int d = cg * 16 + dc;
      int wd = w - d; wd = wd < 0 ? 0 : wd;
      float acc = 0.f;
      #pragma unroll
      for (int c = 0; c < 32; ++c) acc += fabsf(lfr[c] - rfl[c * 256 + wd]);
      u16 v = (w >= d) ? f2h(acc * (1.f / 32.f)) : (u16)0;
      if (dc < 8) lo[dc] = v; else hi[dc - 8] = v;
    }
    *reinterpret_cast<u16x8*>(orow + cg * 4096) = lo;
    *reinterpret_cast<u16x8*>(orow + cg * 4096 + 8) = hi;
  }
}

// ---------------- MFMA implicit-GEMM 3x3 conv ----------------
template<int OC>
__global__ __launch_bounds__(256) void cv_convm(
    const u16* __restrict__ act, const u16* __restrict__ wre,
    const float* __restrict__ bias, u16* __restrict__ yout,
    float* __restrict__ ps, float* __restrict__ pq, int NCG)
{
  constexpr int NF = OC / 16;
  constexpr int NWCH = (5 * OC * 32 * 2) / 1024;

  __shared__ __align__(16) u16 at[4 * 258 * 16];
  __shared__ __align__(16) u16 wl[5 * 64 * 32];
  __shared__ float reds[4][64];
  __shared__ float redq[4][64];

  const int tid = threadIdx.x;
  const int rp = blockIdx.x, b = blockIdx.y;
  const int h0 = rp * 2;
  const int q = tid >> 6, lane = tid & 63;
  const int lanelo = lane & 15, lanehi = lane >> 4;
  const int selB = lane >> 5;
  const int dcb = (lanehi & 1) * 8;
  const int r = q >> 1, hf = q & 1;
  const int wbase = hf * 128 + lanelo;

  if (tid < 128) {
    int tr = tid >> 5, side = (tid >> 4) & 1, dc = tid & 15;
    at[(tr * 258 + side * 257) * 16 + dc] = 0;
  }
  if (h0 == 0)   for (int i = tid; i < 258 * 16; i += 256) at[i] = 0;
  if (h0 == 126) for (int i = tid; i < 258 * 16; i += 256) at[3 * 258 * 16 + i] = 0;

  f32x4 acc[8][NF];
  #pragma unroll
  for (int mf = 0; mf < 8; ++mf)
    #pragma unroll
    for (int nf = 0; nf < NF; ++nf)
      acc[mf][nf] = (f32x4){0.f, 0.f, 0.f, 0.f};

  const int hsrc = h0 - 1 + q;
  const bool rowok = (hsrc >= 0) && (hsrc < 128);

  #pragma unroll 1
  for (int cg = 0; cg < NCG; ++cg) {
    if (rowok) {
      const u16* src = act + ((size_t)((b * 128 + hsrc) * NCG + cg)) * 4096;
      u16* dst = &at[(q * 258 + 1) * 16];
      #pragma unroll
      for (int i = 0; i < 8; ++i)
        gl_lds16(src + i * 512 + lane * 8, dst + i * 512);
    }
    {
      const u16* wsrc = wre + (size_t)cg * (5 * OC * 32);
      for (int ch = q; ch < NWCH; ch += 4)
        gl_lds16(wsrc + ch * 512 + lane * 8, &wl[ch * 512]);
    }
    __syncthreads();

    #pragma unroll
    for (int s = 0; s < 5; ++s) {
      const int tA = 2 * s, tB = (2 * s + 1 < 9) ? (2 * s + 1) : 8;
      const int khA = tA / 3, kwA = tA % 3;
      const int khB = tB / 3, kwB = tB % 3;
      const int kh = selB ? khB : khA;
      const int kw = selB ? kwB : kwA;
      h8 bfr[NF];
      #pragma unroll
      for (int nf = 0; nf < NF; ++nf)
        bfr[nf] = *reinterpret_cast<const h8*>(&wl[(s * OC + nf * 16 + lanelo) * 32 + lanehi * 8]);
      const int abase = ((r + kh) * 258 + wbase + kw) * 16 + dcb;
      #pragma unroll
      for (int mf = 0; mf < 8; ++mf) {
        h8 a = *reinterpret_cast<const h8*>(&at[abase + mf * 256]);
        #pragma unroll
        for (int nf = 0; nf < NF; ++nf)
          acc[mf][nf] = __builtin_amdgcn_mfma_f32_16x16x32_f16(a, bfr[nf], acc[mf][nf], 0, 0, 0);
      }
    }
    __syncthreads();
  }

  // ---- epilogue: bias, BN partial stats, transposed store ----
  #pragma unroll
  for (int nf = 0; nf < NF; ++nf) {
    float bv = bias[nf * 16 + lanelo];
    #pragma unroll
    for (int mf = 0; mf < 8; ++mf)
      #pragma unroll
      for (int e = 0; e < 4; ++e)
        acc[mf][nf][e] += bv;
  }

  float s_[NF], qq[NF];
  #pragma unroll
  for (int nf = 0; nf < NF; ++nf) {
    s_[nf] = 0.f; qq[nf] = 0.f;
    #pragma unroll
    for (int mf = 0; mf < 8; ++mf)
      #pragma unroll
      for (int e = 0; e < 4; ++e) {
        float v = acc[mf][nf][e];
        s_[nf] += v; qq[nf] += v * v;
      }
  }
  #pragma unroll
  for (int nf = 0; nf < NF; ++nf) {
    s_[nf] += __shfl_xor(s_[nf], 16, 64);
    s_[nf] += __shfl_xor(s_[nf], 32, 64);
    qq[nf] += __shfl_xor(qq[nf], 16, 64);
    qq[nf] += __shfl_xor(qq[nf], 32, 64);
  }
  if (lanehi == 0) {
    #pragma unroll
    for (int nf = 0; nf < NF; ++nf) {
      reds[q][nf * 16 + lanelo] = s_[nf];
      redq[q][nf * 16 + lanelo] = qq[nf];
    }
  }
  __syncthreads();
  if (tid < OC) {
    int bid = b * 64 + rp;
    ps[bid * OC + tid] = reds[0][tid] + reds[1][tid] + reds[2][tid] + reds[3][tid];
    pq[bid * OC + tid] = redq[0][tid] + redq[1][tid] + redq[2][tid] + redq[3][tid];
  }

  // FULLY UNROLLED nf loop: all acc[][] indices compile-time (rule #20 —
  // runtime nf here previously demoted the whole acc array to scratch,
  // costing ~930 MB of HBM write traffic per dispatch).
  u16* eb = at;
  #pragma unroll
  for (int nf = 0; nf < NF; ++nf) {
    __syncthreads();
    #pragma unroll
    for (int mf = 0; mf < 8; ++mf)
      #pragma unroll
      for (int e = 0; e < 4; ++e) {
        int px = r * 256 + hf * 128 + mf * 16 + lanehi * 4 + e;
        eb[px * 16 + lanelo] = f2h(acc[mf][nf][e]);
      }
    __syncthreads();
    #pragma unroll
    for (int j = 0; j < 4; ++j) {
      int c = j * 256 + tid;
      int row = c >> 9, off = (c & 511) * 8;
      u16x8 v = *reinterpret_cast<const u16x8*>(&eb[c * 8]);
      *reinterpret_cast<u16x8*>(
          yout + ((size_t)((b * 128 + h0 + row) * NF + nf)) * 4096 + off) = v;
    }
  }
}

// ---------------- finalize BN stats ----------------
__global__ void cv_fin1(const float* __restrict__ p1s, const float* __restrict__ p1q,
                        const float* __restrict__ g, const float* __restrict__ be,
                        float* __restrict__ bn1)
{
  int o = threadIdx.x;
  if (o >= 64) return;
  float s = 0.f, q = 0.f;
  #pragma unroll 4
  for (int k = 0; k < 512; ++k) { s += p1s[k * 64 + o]; q += p1q[k * 64 + o]; }
  float inv = 1.f / 262144.f;
  float mean = s * inv;
  float var = q * inv - mean * mean;
  float a = g[o] * rsqrtf(var + 1e-5f);
  bn1[o] = a;
  bn1[64 + o] = be[o] - mean * a;
}

__global__ void cv_fin2(const float* __restrict__ p2s, const float* __restrict__ p2q,
                        const float* __restrict__ g, const float* __restrict__ be,
                        float* __restrict__ bn2)
{
  int o = threadIdx.x;
  if (o >= 32) return;
  float s = 0.f, q = 0.f;
  #pragma unroll 4
  for (int k = 0; k < 512; ++k) { s += p2s[k * 32 + o]; q += p2q[k * 32 + o]; }
  float inv = 1.f / 262144.f;
  float mean = s * inv;
  float var = q * inv - mean * mean;
  float a = g[o] * rsqrtf(var + 1e-5f);
  bn2[o] = a;
  bn2[32 + o] = be[o] - mean * a;
}

// ---------------- y1 <- relu(bn1(y1)) in place ----------------
__global__ __launch_bounds__(256) void cv_bnrelu1(u16* __restrict__ y1,
                                                  const float* __restrict__ bn1)
{
  size_t i = ((size_t)blockIdx.x * 256 + threadIdx.x) * 8;
  int dc0 = (int)(i & 15);
  int cg = (int)((i >> 12) & 3);
  int o0 = cg * 16 + dc0;
  f32x4 a0 = *reinterpret_cast<const f32x4*>(&bn1[o0]);
  f32x4 a1 = *reinterpret_cast<const f32x4*>(&bn1[o0 + 4]);
  f32x4 s0 = *reinterpret_cast<const f32x4*>(&bn1[64 + o0]);
  f32x4 s1 = *reinterpret_cast<const f32x4*>(&bn1[64 + o0 + 4]);
  u16x8 v = *reinterpret_cast<const u16x8*>(&y1[i]);
  u16x8 outv;
  #pragma unroll
  for (int j = 0; j < 8; ++j) {
    float aj = (j < 4) ? a0[j] : a1[j - 4];
    float sj = (j < 4) ? s0[j] : s1[j - 4];
    float f = fmaxf(fmaf(h2f(v[j]), aj, sj), 0.f);
    outv[j] = f2h(f);
  }
  *reinterpret_cast<u16x8*>(&y1[i]) = outv;
}

// ---------------- deconv ----------------
__global__ __launch_bounds__(256) void cv_deconv(
    const u16* __restrict__ y2, const float* __restrict__ bn2,
    const float* __restrict__ wd, const float* __restrict__ db,
    float* __restrict__ out)
{
  const int tid = threadIdx.x;
  const int blk = blockIdx.x;
  const int b = blk >> 9;
  const int oh = (blk >> 1) & 255;
  const int ow = (blk & 1) * 256 + tid;
  float acc = db[0];
  const int qp = (oh + 1) & 1;
  const int rp = (ow + 1) & 1;
  #pragma unroll
  for (int t = 0; t < 2; ++t) {
    int kh = qp + 2 * t;
    int ih = (oh + 1 - kh) >> 1;
    if (ih < 0 || ih >= 128) continue;
    #pragma unroll
    for (int u = 0; u < 2; ++u) {
      int kw = rp + 2 * u;
      int iw = (ow + 1 - kw) >> 1;
      if (iw < 0 || iw >= 256) continue;
      const u16* base = y2 + (size_t)(b * 128 + ih) * 8192 + iw * 16;
      #pragma unroll
      for (int c = 0; c < 32; ++c) {
        float v = h2f(base[(c >> 4) * 4096 + (c & 15)]);
        float x = fmaxf(fmaf(v, bn2[c], bn2[32 + c]), 0.f);
        acc = fmaf(x, wd[c * 16 + kh * 4 + kw], acc);
      }
    }
  }
  out[(size_t)(b * 256 + oh) * 512 + ow] = acc;
}

// ---------------- launcher ----------------
extern "C" void kernel_launch(void* const* d_in, const int* in_sizes, int n_in,
                              void* d_out, int out_size, void* d_ws, size_t ws_size,
                              hipStream_t stream)
{
  const float* lf  = (const float*)d_in[0];
  const float* rf  = (const float*)d_in[1];
  const float* w1  = (const float*)d_in[2];
  const float* b1  = (const float*)d_in[3];
  const float* g1  = (const float*)d_in[4];
  const float* be1 = (const float*)d_in[5];
  const float* w2  = (const float*)d_in[6];
  const float* b2  = (const float*)d_in[7];
  const float* g2  = (const float*)d_in[8];
  const float* be2 = (const float*)d_in[9];
  const float* wdc = (const float*)d_in[10];
  const float* dbc = (const float*)d_in[11];
  float* out = (float*)d_out;

  char* ws = (char*)d_ws;
  u16* cost  = (u16*)(ws + OFF_COST);
  u16* y1    = (u16*)(ws + OFF_Y1);
  u16* y2    = (u16*)(ws + OFF_Y2);
  u16* w1s   = (u16*)(ws + OFF_W1S);
  u16* w2s   = (u16*)(ws + OFF_W2S);
  float* p1s = (float*)(ws + OFF_P1S);
  float* p1q = (float*)(ws + OFF_P1Q);
  float* p2s = (float*)(ws + OFF_P2S);
  float* p2q = (float*)(ws + OFF_P2Q);
  float* bn1 = (float*)(ws + OFF_BN1);
  float* bn2 = (float*)(ws + OFF_BN2);

  cv_prep<<<dim3(480), dim3(256), 0, stream>>>(w1, w2, w1s, w2s);
  cv_cost<<<dim3(128, 8), dim3(256), 0, stream>>>(lf, rf, cost);
  cv_convm<64><<<dim3(64, 8), dim3(256), 0, stream>>>(cost, w1s, b1, y1, p1s, p1q, 12);
  cv_fin1<<<dim3(1), dim3(64), 0, stream>>>(p1s, p1q, g1, be1, bn1);
  cv_bnrelu1<<<dim3(8192), dim3(256), 0, stream>>>(y1, bn1);
  cv_convm<32><<<dim3(64, 8), dim3(256), 0, stream>>>(y1, w2s, b2, y2, p2s, p2q, 4);
  cv_fin2<<<dim3(1), dim3(64), 0, stream>>>(p2s, p2q, g2, be2, bn2);
  cv_deconv<<<dim3(4096), dim3(256), 0, stream>>>(y2, bn2, wdc, dbc, out);
}

// Round 4
// 335.976 us; speedup vs baseline: 2.9045x; 1.0611x over previous
//
#include <hip/hip_runtime.h>

typedef unsigned short u16;
typedef unsigned int u32;
typedef __attribute__((ext_vector_type(8))) u16 u16x8;
typedef __attribute__((ext_vector_type(4))) float f32x4;
typedef __attribute__((ext_vector_type(8))) _Float16 h8;

#define DEV static __device__ __forceinline__

DEV u16 f2h(float f) {
  union { _Float16 h; u16 u; } v; v.h = (_Float16)f; return v.u;
}
DEV float h2f(u16 u) {
  union { u16 u; _Float16 h; } v; v.u = u; return (float)v.h;
}

DEV void gl_lds16(const void* g, void* l) {
  __builtin_amdgcn_global_load_lds(
      (const __attribute__((address_space(1))) unsigned int*)g,
      (__attribute__((address_space(3))) unsigned int*)l,
      16, 0, 0);
}

// ---------------- workspace layout (bytes) ----------------
static const size_t OFF_COST = 0;
static const size_t OFF_Y1   = 100663296u;
static const size_t OFF_Y2   = 134217728u;
static const size_t OFF_W1S  = 150994944u;
static const size_t OFF_W2S  = 151240704u;
static const size_t OFF_P1S  = 151281664u;
static const size_t OFF_P1Q  = 151412736u;
static const size_t OFF_P2S  = 151543808u;
static const size_t OFF_P2Q  = 151609344u;
static const size_t OFF_BN1  = 151674880u;
static const size_t OFF_BN2  = 151675392u;

// ---------------- weight reorder + f16 convert ----------------
__global__ void cv_prep(const float* __restrict__ w1, const float* __restrict__ w2,
                        u16* __restrict__ w1s, u16* __restrict__ w2s)
{
  int i = blockIdx.x * 256 + threadIdx.x;
  if (i < 122880) {
    int k = i & 31, o = (i >> 5) & 63;
    int s = (i >> 11) % 5, cg = (i >> 11) / 5;
    int slot = k >> 4, dc = k & 15;
    int tap = 2 * s + slot;
    float v = 0.f;
    if (tap < 9) {
      int kh = tap / 3, kw = tap % 3;
      int c = cg * 16 + dc;
      v = w1[((o * 192 + c) * 3 + kh) * 3 + kw];
    }
    w1s[i] = f2h(v);
  }
  if (i < 20480) {
    int k = i & 31, o = (i >> 5) & 31;
    int s = (i >> 10) % 5, cg = (i >> 10) / 5;
    int slot = k >> 4, dc = k & 15;
    int tap = 2 * s + slot;
    float v = 0.f;
    if (tap < 9) {
      int kh = tap / 3, kw = tap % 3;
      int c = cg * 16 + dc;
      v = w2[((o * 64 + c) * 3 + kh) * 3 + kw];
    }
    w2s[i] = f2h(v);
  }
}

// ---------------- cost volume (register-tiled 8d x 4w) ----------------
__global__ __launch_bounds__(256) void cv_cost(const float* __restrict__ lf,
                                               const float* __restrict__ rf,
                                               u16* __restrict__ cost)
{
  __shared__ __align__(16) float smem[32 * 256 + 32 * 272];
  float* lfl  = smem;
  float* rflb = smem + 32 * 256;

  const int tid = threadIdx.x;
  const int lane = tid & 63, q = tid >> 6;
  const int h = blockIdx.x, b = blockIdx.y;

  const size_t gbase = ((size_t)b * 32 * 128 + h) * 256;
  #pragma unroll
  for (int i = 0; i < 8; ++i) {
    int c = q * 8 + i;
    gl_lds16(lf + gbase + (size_t)c * 32768 + lane * 4, &lfl[c * 256]);
    gl_lds16(rf + gbase + (size_t)c * 32768 + lane * 4, &rflb[c * 272 + 16]);
  }
  __syncthreads();

  const int w0 = lane * 4;
  u16* orow = cost + ((size_t)(b * 128 + h)) * 49152 + w0 * 16;

  #pragma unroll 1
  for (int t = 0; t < 6; ++t) {
    const int dblk = t * 4 + q;    // wave-uniform
    const int d0 = dblk * 8;
    float acc[8][4];
    #pragma unroll
    for (int d = 0; d < 8; ++d)
      #pragma unroll
      for (int j = 0; j < 4; ++j) acc[d][j] = 0.f;

    const float* wrow = rflb + 16 + w0 - d0 - 8;
    const float* lrow = lfl + w0;

    #pragma unroll 2
    for (int c = 0; c < 32; ++c) {
      f32x4 lv  = *reinterpret_cast<const f32x4*>(lrow + c * 256);
      f32x4 wv0 = *reinterpret_cast<const f32x4*>(wrow + c * 272);
      f32x4 wv1 = *reinterpret_cast<const f32x4*>(wrow + c * 272 + 4);
      f32x4 wv2 = *reinterpret_cast<const f32x4*>(wrow + c * 272 + 8);
      float win[12];
      #pragma unroll
      for (int e = 0; e < 4; ++e) { win[e] = wv0[e]; win[4 + e] = wv1[e]; win[8 + e] = wv2[e]; }
      #pragma unroll
      for (int d = 0; d < 8; ++d)
        #pragma unroll
        for (int j = 0; j < 4; ++j)
          acc[d][j] += fabsf(lv[j] - win[j - d + 8]);
    }

    const int cg = dblk >> 1, dc0 = (dblk & 1) * 8;
    #pragma unroll
    for (int j = 0; j < 4; ++j) {
      u16x8 pk;
      #pragma unroll
      for (int d = 0; d < 8; ++d) {
        float v = acc[d][j] * (1.f / 32.f);
        pk[d] = (w0 + j >= d0 + d) ? f2h(v) : (u16)0;
      }
      *reinterpret_cast<u16x8*>(orow + cg * 4096 + j * 16 + dc0) = pk;
    }
  }
}

// ---------------- MFMA implicit-GEMM 3x3 conv ----------------
template<int OC>
__global__ __launch_bounds__(256) void cv_convm(
    const u16* __restrict__ act, const u16* __restrict__ wre,
    const float* __restrict__ bias, u16* __restrict__ yout,
    float* __restrict__ ps, float* __restrict__ pq, int NCG)
{
  constexpr int NF = OC / 16;
  constexpr int NWCH = (5 * OC * 32 * 2) / 1024;

  __shared__ __align__(16) u16 at[4 * 258 * 16];
  __shared__ __align__(16) u16 wl[5 * 64 * 32];
  __shared__ float reds[4][64];
  __shared__ float redq[4][64];

  const int tid = threadIdx.x;
  const int rp = blockIdx.x, b = blockIdx.y;
  const int h0 = rp * 2;
  const int q = tid >> 6, lane = tid & 63;
  const int lanelo = lane & 15, lanehi = lane >> 4;
  const int selB = lane >> 5;
  const int dcb = (lanehi & 1) * 8;
  const int r = q >> 1, hf = q & 1;
  const int wbase = hf * 128 + lanelo;

  if (tid < 128) {
    int tr = tid >> 5, side = (tid >> 4) & 1, dc = tid & 15;
    at[(tr * 258 + side * 257) * 16 + dc] = 0;
  }
  if (h0 == 0)   for (int i = tid; i < 258 * 16; i += 256) at[i] = 0;
  if (h0 == 126) for (int i = tid; i < 258 * 16; i += 256) at[3 * 258 * 16 + i] = 0;

  f32x4 acc[8][NF];
  #pragma unroll
  for (int mf = 0; mf < 8; ++mf)
    #pragma unroll
    for (int nf = 0; nf < NF; ++nf)
      acc[mf][nf] = (f32x4){0.f, 0.f, 0.f, 0.f};

  const int hsrc = h0 - 1 + q;
  const bool rowok = (hsrc >= 0) && (hsrc < 128);

  #pragma unroll 1
  for (int cg = 0; cg < NCG; ++cg) {
    if (rowok) {
      const u16* src = act + ((size_t)((b * 128 + hsrc) * NCG + cg)) * 4096;
      u16* dst = &at[(q * 258 + 1) * 16];
      #pragma unroll
      for (int i = 0; i < 8; ++i)
        gl_lds16(src + i * 512 + lane * 8, dst + i * 512);
    }
    {
      const u16* wsrc = wre + (size_t)cg * (5 * OC * 32);
      for (int ch = q; ch < NWCH; ch += 4)
        gl_lds16(wsrc + ch * 512 + lane * 8, &wl[ch * 512]);
    }
    __syncthreads();

    #pragma unroll
    for (int s = 0; s < 5; ++s) {
      const int tA = 2 * s, tB = (2 * s + 1 < 9) ? (2 * s + 1) : 8;
      const int khA = tA / 3, kwA = tA % 3;
      const int khB = tB / 3, kwB = tB % 3;
      const int kh = selB ? khB : khA;
      const int kw = selB ? kwB : kwA;
      h8 bfr[NF];
      #pragma unroll
      for (int nf = 0; nf < NF; ++nf)
        bfr[nf] = *reinterpret_cast<const h8*>(&wl[(s * OC + nf * 16 + lanelo) * 32 + lanehi * 8]);
      const int abase = ((r + kh) * 258 + wbase + kw) * 16 + dcb;
      #pragma unroll
      for (int mf = 0; mf < 8; ++mf) {
        h8 a = *reinterpret_cast<const h8*>(&at[abase + mf * 256]);
        #pragma unroll
        for (int nf = 0; nf < NF; ++nf)
          acc[mf][nf] = __builtin_amdgcn_mfma_f32_16x16x32_f16(a, bfr[nf], acc[mf][nf], 0, 0, 0);
      }
    }
    __syncthreads();
  }

  #pragma unroll
  for (int nf = 0; nf < NF; ++nf) {
    float bv = bias[nf * 16 + lanelo];
    #pragma unroll
    for (int mf = 0; mf < 8; ++mf)
      #pragma unroll
      for (int e = 0; e < 4; ++e)
        acc[mf][nf][e] += bv;
  }

  float s_[NF], qq[NF];
  #pragma unroll
  for (int nf = 0; nf < NF; ++nf) {
    s_[nf] = 0.f; qq[nf] = 0.f;
    #pragma unroll
    for (int mf = 0; mf < 8; ++mf)
      #pragma unroll
      for (int e = 0; e < 4; ++e) {
        float v = acc[mf][nf][e];
        s_[nf] += v; qq[nf] += v * v;
      }
  }
  #pragma unroll
  for (int nf = 0; nf < NF; ++nf) {
    s_[nf] += __shfl_xor(s_[nf], 16, 64);
    s_[nf] += __shfl_xor(s_[nf], 32, 64);
    qq[nf] += __shfl_xor(qq[nf], 16, 64);
    qq[nf] += __shfl_xor(qq[nf], 32, 64);
  }
  if (lanehi == 0) {
    #pragma unroll
    for (int nf = 0; nf < NF; ++nf) {
      reds[q][nf * 16 + lanelo] = s_[nf];
      redq[q][nf * 16 + lanelo] = qq[nf];
    }
  }
  __syncthreads();
  if (tid < OC) {
    int bid = b * 64 + rp;
    ps[bid * OC + tid] = reds[0][tid] + reds[1][tid] + reds[2][tid] + reds[3][tid];
    pq[bid * OC + tid] = redq[0][tid] + redq[1][tid] + redq[2][tid] + redq[3][tid];
  }

  u16* eb = at;
  #pragma unroll
  for (int nf = 0; nf < NF; ++nf) {
    __syncthreads();
    #pragma unroll
    for (int mf = 0; mf < 8; ++mf)
      #pragma unroll
      for (int e = 0; e < 4; ++e) {
        int px = r * 256 + hf * 128 + mf * 16 + lanehi * 4 + e;
        eb[px * 16 + lanelo] = f2h(acc[mf][nf][e]);
      }
    __syncthreads();
    #pragma unroll
    for (int j = 0; j < 4; ++j) {
      int c = j * 256 + tid;
      int row = c >> 9, off = (c & 511) * 8;
      u16x8 v = *reinterpret_cast<const u16x8*>(&eb[c * 8]);
      *reinterpret_cast<u16x8*>(
          yout + ((size_t)((b * 128 + h0 + row) * NF + nf)) * 4096 + off) = v;
    }
  }
}

// ---------------- finalize BN stats ----------------
__global__ void cv_fin1(const float* __restrict__ p1s, const float* __restrict__ p1q,
                        const float* __restrict__ g, const float* __restrict__ be,
                        float* __restrict__ bn1)
{
  int o = threadIdx.x;
  if (o >= 64) return;
  float s = 0.f, q = 0.f;
  #pragma unroll 4
  for (int k = 0; k < 512; ++k) { s += p1s[k * 64 + o]; q += p1q[k * 64 + o]; }
  float inv = 1.f / 262144.f;
  float mean = s * inv;
  float var = q * inv - mean * mean;
  float a = g[o] * rsqrtf(var + 1e-5f);
  bn1[o] = a;
  bn1[64 + o] = be[o] - mean * a;
}

__global__ void cv_fin2(const float* __restrict__ p2s, const float* __restrict__ p2q,
                        const float* __restrict__ g, const float* __restrict__ be,
                        float* __restrict__ bn2)
{
  int o = threadIdx.x;
  if (o >= 32) return;
  float s = 0.f, q = 0.f;
  #pragma unroll 4
  for (int k = 0; k < 512; ++k) { s += p2s[k * 32 + o]; q += p2q[k * 32 + o]; }
  float inv = 1.f / 262144.f;
  float mean = s * inv;
  float var = q * inv - mean * mean;
  float a = g[o] * rsqrtf(var + 1e-5f);
  bn2[o] = a;
  bn2[32 + o] = be[o] - mean * a;
}

// ---------------- y1 <- relu(bn1(y1)) in place ----------------
__global__ __launch_bounds__(256) void cv_bnrelu1(u16* __restrict__ y1,
                                                  const float* __restrict__ bn1)
{
  size_t i = ((size_t)blockIdx.x * 256 + threadIdx.x) * 8;
  int dc0 = (int)(i & 15);
  int cg = (int)((i >> 12) & 3);
  int o0 = cg * 16 + dc0;
  f32x4 a0 = *reinterpret_cast<const f32x4*>(&bn1[o0]);
  f32x4 a1 = *reinterpret_cast<const f32x4*>(&bn1[o0 + 4]);
  f32x4 s0 = *reinterpret_cast<const f32x4*>(&bn1[64 + o0]);
  f32x4 s1 = *reinterpret_cast<const f32x4*>(&bn1[64 + o0 + 4]);
  u16x8 v = *reinterpret_cast<const u16x8*>(&y1[i]);
  u16x8 outv;
  #pragma unroll
  for (int j = 0; j < 8; ++j) {
    float aj = (j < 4) ? a0[j] : a1[j - 4];
    float sj = (j < 4) ? s0[j] : s1[j - 4];
    float f = fmaxf(fmaf(h2f(v[j]), aj, sj), 0.f);
    outv[j] = f2h(f);
  }
  *reinterpret_cast<u16x8*>(&y1[i]) = outv;
}

// ---------------- deconv ----------------
__global__ __launch_bounds__(256) void cv_deconv(
    const u16* __restrict__ y2, const float* __restrict__ bn2,
    const float* __restrict__ wd, const float* __restrict__ db,
    float* __restrict__ out)
{
  const int tid = threadIdx.x;
  const int blk = blockIdx.x;
  const int b = blk >> 9;
  const int oh = (blk >> 1) & 255;
  const int ow = (blk & 1) * 256 + tid;
  float acc = db[0];
  const int qp = (oh + 1) & 1;
  const int rp = (ow + 1) & 1;
  #pragma unroll
  for (int t = 0; t < 2; ++t) {
    int kh = qp + 2 * t;
    int ih = (oh + 1 - kh) >> 1;
    if (ih < 0 || ih >= 128) continue;
    #pragma unroll
    for (int u = 0; u < 2; ++u) {
      int kw = rp + 2 * u;
      int iw = (ow + 1 - kw) >> 1;
      if (iw < 0 || iw >= 256) continue;
      const u16* base = y2 + (size_t)(b * 128 + ih) * 8192 + iw * 16;
      #pragma unroll
      for (int c = 0; c < 32; ++c) {
        float v = h2f(base[(c >> 4) * 4096 + (c & 15)]);
        float x = fmaxf(fmaf(v, bn2[c], bn2[32 + c]), 0.f);
        acc = fmaf(x, wd[c * 16 + kh * 4 + kw], acc);
      }
    }
  }
  out[(size_t)(b * 256 + oh) * 512 + ow] = acc;
}

// ---------------- launcher ----------------
extern "C" void kernel_launch(void* const* d_in, const int* in_sizes, int n_in,
                              void* d_out, int out_size, void* d_ws, size_t ws_size,
                              hipStream_t stream)
{
  const float* lf  = (const float*)d_in[0];
  const float* rf  = (const float*)d_in[1];
  const float* w1  = (const float*)d_in[2];
  const float* b1  = (const float*)d_in[3];
  const float* g1  = (const float*)d_in[4];
  const float* be1 = (const float*)d_in[5];
  const float* w2  = (const float*)d_in[6];
  const float* b2  = (const float*)d_in[7];
  const float* g2  = (const float*)d_in[8];
  const float* be2 = (const float*)d_in[9];
  const float* wdc = (const float*)d_in[10];
  const float* dbc = (const float*)d_in[11];
  float* out = (float*)d_out;

  char* ws = (char*)d_ws;
  u16* cost  = (u16*)(ws + OFF_COST);
  u16* y1    = (u16*)(ws + OFF_Y1);
  u16* y2    = (u16*)(ws + OFF_Y2);
  u16* w1s   = (u16*)(ws + OFF_W1S);
  u16* w2s   = (u16*)(ws + OFF_W2S);
  float* p1s = (float*)(ws + OFF_P1S);
  float* p1q = (float*)(ws + OFF_P1Q);
  float* p2s = (float*)(ws + OFF_P2S);
  float* p2q = (float*)(ws + OFF_P2Q);
  float* bn1 = (float*)(ws + OFF_BN1);
  float* bn2 = (float*)(ws + OFF_BN2);

  cv_prep<<<dim3(480), dim3(256), 0, stream>>>(w1, w2, w1s, w2s);
  cv_cost<<<dim3(128, 8), dim3(256), 0, stream>>>(lf, rf, cost);
  cv_convm<64><<<dim3(64, 8), dim3(256), 0, stream>>>(cost, w1s, b1, y1, p1s, p1q, 12);
  cv_fin1<<<dim3(1), dim3(64), 0, stream>>>(p1s, p1q, g1, be1, bn1);
  cv_bnrelu1<<<dim3(8192), dim3(256), 0, stream>>>(y1, bn1);
  cv_convm<32><<<dim3(64, 8), dim3(256), 0, stream>>>(y1, w2s, b2, y2, p2s, p2q, 4);
  cv_fin2<<<dim3(1), dim3(64), 0, stream>>>(p2s, p2q, g2, be2, bn2);
  cv_deconv<<<dim3(4096), dim3(256), 0, stream>>>(y2, bn2, wdc, dbc, out);
}

// Round 5
// 324.689 us; speedup vs baseline: 3.0055x; 1.0348x over previous
//
#include <hip/hip_runtime.h>

typedef unsigned short u16;
typedef unsigned int u32;
typedef __attribute__((ext_vector_type(8))) u16 u16x8;
typedef __attribute__((ext_vector_type(4))) float f32x4;
typedef __attribute__((ext_vector_type(8))) _Float16 h8;

#define DEV static __device__ __forceinline__

DEV u16 f2h(float f) {
  union { _Float16 h; u16 u; } v; v.h = (_Float16)f; return v.u;
}
DEV float h2f(u16 u) {
  union { u16 u; _Float16 h; } v; v.u = u; return (float)v.h;
}

DEV void gl_lds16(const void* g, void* l) {
  __builtin_amdgcn_global_load_lds(
      (const __attribute__((address_space(1))) unsigned int*)g,
      (__attribute__((address_space(3))) unsigned int*)l,
      16, 0, 0);
}

// ---------------- workspace layout (bytes) ----------------
static const size_t OFF_COST = 0;
static const size_t OFF_Y1   = 100663296u;
static const size_t OFF_Y2   = 134217728u;
static const size_t OFF_W1S  = 150994944u;
static const size_t OFF_W2S  = 151240704u;
static const size_t OFF_P1S  = 151281664u;
static const size_t OFF_P1Q  = 151412736u;
static const size_t OFF_P2S  = 151543808u;
static const size_t OFF_P2Q  = 151609344u;
static const size_t OFF_BN1  = 151674880u;
static const size_t OFF_BN2  = 151675392u;

// ---------------- weight reorder + f16 convert ----------------
__global__ void cv_prep(const float* __restrict__ w1, const float* __restrict__ w2,
                        u16* __restrict__ w1s, u16* __restrict__ w2s)
{
  int i = blockIdx.x * 256 + threadIdx.x;
  if (i < 122880) {
    int k = i & 31, o = (i >> 5) & 63;
    int s = (i >> 11) % 5, cg = (i >> 11) / 5;
    int slot = k >> 4, dc = k & 15;
    int tap = 2 * s + slot;
    float v = 0.f;
    if (tap < 9) {
      int kh = tap / 3, kw = tap % 3;
      int c = cg * 16 + dc;
      v = w1[((o * 192 + c) * 3 + kh) * 3 + kw];
    }
    w1s[i] = f2h(v);
  }
  if (i < 20480) {
    int k = i & 31, o = (i >> 5) & 31;
    int s = (i >> 10) % 5, cg = (i >> 10) / 5;
    int slot = k >> 4, dc = k & 15;
    int tap = 2 * s + slot;
    float v = 0.f;
    if (tap < 9) {
      int kh = tap / 3, kw = tap % 3;
      int c = cg * 16 + dc;
      v = w2[((o * 64 + c) * 3 + kh) * 3 + kw];
    }
    w2s[i] = f2h(v);
  }
}

// ---------------- cost volume (register-tiled 8d x 4w, 8 waves/block) ----------------
// 512 threads: 8 waves stage all 32 channels once, then each wave owns 3 of
// the 24 disparity-blocks. LDS/block unchanged (2 blocks/CU) but 16 waves/CU
// (4/SIMD) for latency hiding -- the round-4 version was occupancy-bound at
// 2 waves/SIMD.
__global__ __launch_bounds__(512) void cv_cost(const float* __restrict__ lf,
                                               const float* __restrict__ rf,
                                               u16* __restrict__ cost)
{
  __shared__ __align__(16) float smem[32 * 256 + 32 * 272];
  float* lfl  = smem;
  float* rflb = smem + 32 * 256;

  const int tid = threadIdx.x;
  const int lane = tid & 63, q = tid >> 6;   // q in 0..7
  const int h = blockIdx.x, b = blockIdx.y;

  const size_t gbase = ((size_t)b * 32 * 128 + h) * 256;
  #pragma unroll
  for (int i = 0; i < 4; ++i) {
    int c = q * 4 + i;
    gl_lds16(lf + gbase + (size_t)c * 32768 + lane * 4, &lfl[c * 256]);
    gl_lds16(rf + gbase + (size_t)c * 32768 + lane * 4, &rflb[c * 272 + 16]);
  }
  __syncthreads();

  const int w0 = lane * 4;
  u16* orow = cost + ((size_t)(b * 128 + h)) * 49152 + w0 * 16;

  #pragma unroll 1
  for (int t = 0; t < 3; ++t) {
    const int dblk = t * 8 + q;    // wave-uniform, 0..23
    const int d0 = dblk * 8;
    float acc[8][4];
    #pragma unroll
    for (int d = 0; d < 8; ++d)
      #pragma unroll
      for (int j = 0; j < 4; ++j) acc[d][j] = 0.f;

    const float* wrow = rflb + 16 + w0 - d0 - 8;  // win[i] = rf[w0-d0-8+i]
    const float* lrow = lfl + w0;

    #pragma unroll 2
    for (int c = 0; c < 32; ++c) {
      f32x4 lv  = *reinterpret_cast<const f32x4*>(lrow + c * 256);
      f32x4 wv0 = *reinterpret_cast<const f32x4*>(wrow + c * 272);
      f32x4 wv1 = *reinterpret_cast<const f32x4*>(wrow + c * 272 + 4);
      f32x4 wv2 = *reinterpret_cast<const f32x4*>(wrow + c * 272 + 8);
      float win[12];
      #pragma unroll
      for (int e = 0; e < 4; ++e) { win[e] = wv0[e]; win[4 + e] = wv1[e]; win[8 + e] = wv2[e]; }
      #pragma unroll
      for (int d = 0; d < 8; ++d)
        #pragma unroll
        for (int j = 0; j < 4; ++j)
          acc[d][j] += fabsf(lv[j] - win[j - d + 8]);
    }

    const int cg = dblk >> 1, dc0 = (dblk & 1) * 8;
    #pragma unroll
    for (int j = 0; j < 4; ++j) {
      u16x8 pk;
      #pragma unroll
      for (int d = 0; d < 8; ++d) {
        float v = acc[d][j] * (1.f / 32.f);
        pk[d] = (w0 + j >= d0 + d) ? f2h(v) : (u16)0;
      }
      *reinterpret_cast<u16x8*>(orow + cg * 4096 + j * 16 + dc0) = pk;
    }
  }
}

// ---------------- MFMA implicit-GEMM 3x3 conv ----------------
template<int OC>
__global__ __launch_bounds__(256) void cv_convm(
    const u16* __restrict__ act, const u16* __restrict__ wre,
    const float* __restrict__ bias, u16* __restrict__ yout,
    float* __restrict__ ps, float* __restrict__ pq, int NCG)
{
  constexpr int NF = OC / 16;
  constexpr int NWCH = (5 * OC * 32 * 2) / 1024;

  __shared__ __align__(16) u16 at[4 * 258 * 16];
  __shared__ __align__(16) u16 wl[5 * 64 * 32];
  __shared__ float reds[4][64];
  __shared__ float redq[4][64];

  const int tid = threadIdx.x;
  const int rp = blockIdx.x, b = blockIdx.y;
  const int h0 = rp * 2;
  const int q = tid >> 6, lane = tid & 63;
  const int lanelo = lane & 15, lanehi = lane >> 4;
  const int selB = lane >> 5;
  const int dcb = (lanehi & 1) * 8;
  const int r = q >> 1, hf = q & 1;
  const int wbase = hf * 128 + lanelo;

  if (tid < 128) {
    int tr = tid >> 5, side = (tid >> 4) & 1, dc = tid & 15;
    at[(tr * 258 + side * 257) * 16 + dc] = 0;
  }
  if (h0 == 0)   for (int i = tid; i < 258 * 16; i += 256) at[i] = 0;
  if (h0 == 126) for (int i = tid; i < 258 * 16; i += 256) at[3 * 258 * 16 + i] = 0;

  f32x4 acc[8][NF];
  #pragma unroll
  for (int mf = 0; mf < 8; ++mf)
    #pragma unroll
    for (int nf = 0; nf < NF; ++nf)
      acc[mf][nf] = (f32x4){0.f, 0.f, 0.f, 0.f};

  const int hsrc = h0 - 1 + q;
  const bool rowok = (hsrc >= 0) && (hsrc < 128);

  #pragma unroll 1
  for (int cg = 0; cg < NCG; ++cg) {
    if (rowok) {
      const u16* src = act + ((size_t)((b * 128 + hsrc) * NCG + cg)) * 4096;
      u16* dst = &at[(q * 258 + 1) * 16];
      #pragma unroll
      for (int i = 0; i < 8; ++i)
        gl_lds16(src + i * 512 + lane * 8, dst + i * 512);
    }
    {
      const u16* wsrc = wre + (size_t)cg * (5 * OC * 32);
      for (int ch = q; ch < NWCH; ch += 4)
        gl_lds16(wsrc + ch * 512 + lane * 8, &wl[ch * 512]);
    }
    __syncthreads();

    #pragma unroll
    for (int s = 0; s < 5; ++s) {
      const int tA = 2 * s, tB = (2 * s + 1 < 9) ? (2 * s + 1) : 8;
      const int khA = tA / 3, kwA = tA % 3;
      const int khB = tB / 3, kwB = tB % 3;
      const int kh = selB ? khB : khA;
      const int kw = selB ? kwB : kwA;
      h8 bfr[NF];
      #pragma unroll
      for (int nf = 0; nf < NF; ++nf)
        bfr[nf] = *reinterpret_cast<const h8*>(&wl[(s * OC + nf * 16 + lanelo) * 32 + lanehi * 8]);
      const int abase = ((r + kh) * 258 + wbase + kw) * 16 + dcb;
      #pragma unroll
      for (int mf = 0; mf < 8; ++mf) {
        h8 a = *reinterpret_cast<const h8*>(&at[abase + mf * 256]);
        #pragma unroll
        for (int nf = 0; nf < NF; ++nf)
          acc[mf][nf] = __builtin_amdgcn_mfma_f32_16x16x32_f16(a, bfr[nf], acc[mf][nf], 0, 0, 0);
      }
    }
    __syncthreads();
  }

  #pragma unroll
  for (int nf = 0; nf < NF; ++nf) {
    float bv = bias[nf * 16 + lanelo];
    #pragma unroll
    for (int mf = 0; mf < 8; ++mf)
      #pragma unroll
      for (int e = 0; e < 4; ++e)
        acc[mf][nf][e] += bv;
  }

  float s_[NF], qq[NF];
  #pragma unroll
  for (int nf = 0; nf < NF; ++nf) {
    s_[nf] = 0.f; qq[nf] = 0.f;
    #pragma unroll
    for (int mf = 0; mf < 8; ++mf)
      #pragma unroll
      for (int e = 0; e < 4; ++e) {
        float v = acc[mf][nf][e];
        s_[nf] += v; qq[nf] += v * v;
      }
  }
  #pragma unroll
  for (int nf = 0; nf < NF; ++nf) {
    s_[nf] += __shfl_xor(s_[nf], 16, 64);
    s_[nf] += __shfl_xor(s_[nf], 32, 64);
    qq[nf] += __shfl_xor(qq[nf], 16, 64);
    qq[nf] += __shfl_xor(qq[nf], 32, 64);
  }
  if (lanehi == 0) {
    #pragma unroll
    for (int nf = 0; nf < NF; ++nf) {
      reds[q][nf * 16 + lanelo] = s_[nf];
      redq[q][nf * 16 + lanelo] = qq[nf];
    }
  }
  __syncthreads();
  if (tid < OC) {
    int bid = b * 64 + rp;
    ps[bid * OC + tid] = reds[0][tid] + reds[1][tid] + reds[2][tid] + reds[3][tid];
    pq[bid * OC + tid] = redq[0][tid] + redq[1][tid] + redq[2][tid] + redq[3][tid];
  }

  u16* eb = at;
  #pragma unroll
  for (int nf = 0; nf < NF; ++nf) {
    __syncthreads();
    #pragma unroll
    for (int mf = 0; mf < 8; ++mf)
      #pragma unroll
      for (int e = 0; e < 4; ++e) {
        int px = r * 256 + hf * 128 + mf * 16 + lanehi * 4 + e;
        eb[px * 16 + lanelo] = f2h(acc[mf][nf][e]);
      }
    __syncthreads();
    #pragma unroll
    for (int j = 0; j < 4; ++j) {
      int c = j * 256 + tid;
      int row = c >> 9, off = (c & 511) * 8;
      u16x8 v = *reinterpret_cast<const u16x8*>(&eb[c * 8]);
      *reinterpret_cast<u16x8*>(
          yout + ((size_t)((b * 128 + h0 + row) * NF + nf)) * 4096 + off) = v;
    }
  }
}

// ---------------- finalize BN stats ----------------
__global__ void cv_fin1(const float* __restrict__ p1s, const float* __restrict__ p1q,
                        const float* __restrict__ g, const float* __restrict__ be,
                        float* __restrict__ bn1)
{
  int o = threadIdx.x;
  if (o >= 64) return;
  float s = 0.f, q = 0.f;
  #pragma unroll 4
  for (int k = 0; k < 512; ++k) { s += p1s[k * 64 + o]; q += p1q[k * 64 + o]; }
  float inv = 1.f / 262144.f;
  float mean = s * inv;
  float var = q * inv - mean * mean;
  float a = g[o] * rsqrtf(var + 1e-5f);
  bn1[o] = a;
  bn1[64 + o] = be[o] - mean * a;
}

__global__ void cv_fin2(const float* __restrict__ p2s, const float* __restrict__ p2q,
                        const float* __restrict__ g, const float* __restrict__ be,
                        float* __restrict__ bn2)
{
  int o = threadIdx.x;
  if (o >= 32) return;
  float s = 0.f, q = 0.f;
  #pragma unroll 4
  for (int k = 0; k < 512; ++k) { s += p2s[k * 32 + o]; q += p2q[k * 32 + o]; }
  float inv = 1.f / 262144.f;
  float mean = s * inv;
  float var = q * inv - mean * mean;
  float a = g[o] * rsqrtf(var + 1e-5f);
  bn2[o] = a;
  bn2[32 + o] = be[o] - mean * a;
}

// ---------------- y1 <- relu(bn1(y1)) in place ----------------
__global__ __launch_bounds__(256) void cv_bnrelu1(u16* __restrict__ y1,
                                                  const float* __restrict__ bn1)
{
  size_t i = ((size_t)blockIdx.x * 256 + threadIdx.x) * 8;
  int dc0 = (int)(i & 15);
  int cg = (int)((i >> 12) & 3);
  int o0 = cg * 16 + dc0;
  f32x4 a0 = *reinterpret_cast<const f32x4*>(&bn1[o0]);
  f32x4 a1 = *reinterpret_cast<const f32x4*>(&bn1[o0 + 4]);
  f32x4 s0 = *reinterpret_cast<const f32x4*>(&bn1[64 + o0]);
  f32x4 s1 = *reinterpret_cast<const f32x4*>(&bn1[64 + o0 + 4]);
  u16x8 v = *reinterpret_cast<const u16x8*>(&y1[i]);
  u16x8 outv;
  #pragma unroll
  for (int j = 0; j < 8; ++j) {
    float aj = (j < 4) ? a0[j] : a1[j - 4];
    float sj = (j < 4) ? s0[j] : s1[j - 4];
    float f = fmaxf(fmaf(h2f(v[j]), aj, sj), 0.f);
    outv[j] = f2h(f);
  }
  *reinterpret_cast<u16x8*>(&y1[i]) = outv;
}

// ---------------- deconv ----------------
__global__ __launch_bounds__(256) void cv_deconv(
    const u16* __restrict__ y2, const float* __restrict__ bn2,
    const float* __restrict__ wd, const float* __restrict__ db,
    float* __restrict__ out)
{
  const int tid = threadIdx.x;
  const int blk = blockIdx.x;
  const int b = blk >> 9;
  const int oh = (blk >> 1) & 255;
  const int ow = (blk & 1) * 256 + tid;
  float acc = db[0];
  const int qp = (oh + 1) & 1;
  const int rp = (ow + 1) & 1;
  #pragma unroll
  for (int t = 0; t < 2; ++t) {
    int kh = qp + 2 * t;
    int ih = (oh + 1 - kh) >> 1;
    if (ih < 0 || ih >= 128) continue;
    #pragma unroll
    for (int u = 0; u < 2; ++u) {
      int kw = rp + 2 * u;
      int iw = (ow + 1 - kw) >> 1;
      if (iw < 0 || iw >= 256) continue;
      const u16* base = y2 + (size_t)(b * 128 + ih) * 8192 + iw * 16;
      #pragma unroll
      for (int c = 0; c < 32; ++c) {
        float v = h2f(base[(c >> 4) * 4096 + (c & 15)]);
        float x = fmaxf(fmaf(v, bn2[c], bn2[32 + c]), 0.f);
        acc = fmaf(x, wd[c * 16 + kh * 4 + kw], acc);
      }
    }
  }
  out[(size_t)(b * 256 + oh) * 512 + ow] = acc;
}

// ---------------- launcher ----------------
extern "C" void kernel_launch(void* const* d_in, const int* in_sizes, int n_in,
                              void* d_out, int out_size, void* d_ws, size_t ws_size,
                              hipStream_t stream)
{
  const float* lf  = (const float*)d_in[0];
  const float* rf  = (const float*)d_in[1];
  const float* w1  = (const float*)d_in[2];
  const float* b1  = (const float*)d_in[3];
  const float* g1  = (const float*)d_in[4];
  const float* be1 = (const float*)d_in[5];
  const float* w2  = (const float*)d_in[6];
  const float* b2  = (const float*)d_in[7];
  const float* g2  = (const float*)d_in[8];
  const float* be2 = (const float*)d_in[9];
  const float* wdc = (const float*)d_in[10];
  const float* dbc = (const float*)d_in[11];
  float* out = (float*)d_out;

  char* ws = (char*)d_ws;
  u16* cost  = (u16*)(ws + OFF_COST);
  u16* y1    = (u16*)(ws + OFF_Y1);
  u16* y2    = (u16*)(ws + OFF_Y2);
  u16* w1s   = (u16*)(ws + OFF_W1S);
  u16* w2s   = (u16*)(ws + OFF_W2S);
  float* p1s = (float*)(ws + OFF_P1S);
  float* p1q = (float*)(ws + OFF_P1Q);
  float* p2s = (float*)(ws + OFF_P2S);
  float* p2q = (float*)(ws + OFF_P2Q);
  float* bn1 = (float*)(ws + OFF_BN1);
  float* bn2 = (float*)(ws + OFF_BN2);

  cv_prep<<<dim3(480), dim3(256), 0, stream>>>(w1, w2, w1s, w2s);
  cv_cost<<<dim3(128, 8), dim3(512), 0, stream>>>(lf, rf, cost);
  cv_convm<64><<<dim3(64, 8), dim3(256), 0, stream>>>(cost, w1s, b1, y1, p1s, p1q, 12);
  cv_fin1<<<dim3(1), dim3(64), 0, stream>>>(p1s, p1q, g1, be1, bn1);
  cv_bnrelu1<<<dim3(8192), dim3(256), 0, stream>>>(y1, bn1);
  cv_convm<32><<<dim3(64, 8), dim3(256), 0, stream>>>(y1, w2s, b2, y2, p2s, p2q, 4);
  cv_fin2<<<dim3(1), dim3(64), 0, stream>>>(p2s, p2q, g2, be2, bn2);
  cv_deconv<<<dim3(4096), dim3(256), 0, stream>>>(y2, bn2, wdc, dbc, out);
}

// Round 7
// 290.277 us; speedup vs baseline: 3.3618x; 1.1185x over previous
//
#include <hip/hip_runtime.h>

typedef unsigned short u16;
typedef unsigned int u32;
typedef __attribute__((ext_vector_type(8))) u16 u16x8;
typedef __attribute__((ext_vector_type(4))) u32 u32x4;
typedef __attribute__((ext_vector_type(4))) float f32x4;
typedef __attribute__((ext_vector_type(8))) _Float16 h8;
typedef __attribute__((ext_vector_type(2))) _Float16 h2;
typedef __attribute__((ext_vector_type(2))) __fp16 fp16x2;  // cvt_pkrtz return type

#define DEV static __device__ __forceinline__

DEV u16 f2h(float f) {
  union { _Float16 h; u16 u; } v; v.h = (_Float16)f; return v.u;
}
DEV float h2f(u16 u) {
  union { u16 u; _Float16 h; } v; v.u = u; return (float)v.h;
}
DEV h2 u2h2(u32 x) { union { u32 u; h2 h; } v; v.u = x; return v.h; }
DEV u32 h22u(h2 x) { union { u32 u; h2 h; } v; v.h = x; return v.u; }
DEV u32 pk2u(fp16x2 x) { union { u32 u; fp16x2 h; } v; v.h = x; return v.u; }

DEV void gl_lds16(const void* g, void* l) {
  __builtin_amdgcn_global_load_lds(
      (const __attribute__((address_space(1))) unsigned int*)g,
      (__attribute__((address_space(3))) unsigned int*)l,
      16, 0, 0);
}

// ---------------- workspace layout (bytes) ----------------
static const size_t OFF_COST = 0;
static const size_t OFF_Y1   = 100663296u;
static const size_t OFF_Y2   = 134217728u;
static const size_t OFF_W1S  = 150994944u;
static const size_t OFF_W2S  = 151240704u;
static const size_t OFF_P1S  = 151281664u;
static const size_t OFF_P1Q  = 151412736u;
static const size_t OFF_P2S  = 151543808u;
static const size_t OFF_P2Q  = 151609344u;
static const size_t OFF_BN1  = 151674880u;
static const size_t OFF_BN2  = 151675392u;

// ---------------- weight reorder + f16 convert ----------------
__global__ void cv_prep(const float* __restrict__ w1, const float* __restrict__ w2,
                        u16* __restrict__ w1s, u16* __restrict__ w2s)
{
  int i = blockIdx.x * 256 + threadIdx.x;
  if (i < 122880) {
    int k = i & 31, o = (i >> 5) & 63;
    int s = (i >> 11) % 5, cg = (i >> 11) / 5;
    int slot = k >> 4, dc = k & 15;
    int tap = 2 * s + slot;
    float v = 0.f;
    if (tap < 9) {
      int kh = tap / 3, kw = tap % 3;
      int c = cg * 16 + dc;
      v = w1[((o * 192 + c) * 3 + kh) * 3 + kw];
    }
    w1s[i] = f2h(v);
  }
  if (i < 20480) {
    int k = i & 31, o = (i >> 5) & 31;
    int s = (i >> 10) % 5, cg = (i >> 10) / 5;
    int slot = k >> 4, dc = k & 15;
    int tap = 2 * s + slot;
    float v = 0.f;
    if (tap < 9) {
      int kh = tap / 3, kw = tap % 3;
      int c = cg * 16 + dc;
      v = w2[((o * 64 + c) * 3 + kh) * 3 + kw];
    }
    w2s[i] = f2h(v);
  }
}

// ---------------- cost volume (packed-f16 dot2 SAD, 8d x 4w tiles) ----------------
// LDS: lfp u32[16][256] (channel-pair f16), rfp u32[16][272] right after it.
// Per (d,j) per channel-pair: v_pk_add_f16(neg) + v_and(abs) + v_dot2_f32_f16
// = 1.5 VALU instr per element (vs ~3 for scalar f32 path). LDS reads also
// halved; 33.8 KB/block -> up to 4 blocks/CU.
__global__ __launch_bounds__(512, 4) void cv_cost(const float* __restrict__ lf,
                                                  const float* __restrict__ rf,
                                                  u16* __restrict__ cost)
{
  __shared__ __align__(16) u32 smem[16 * 256 + 16 * 272];  // lfp | rfp
  u32* lfp = smem;
  u32* rfp = smem + 16 * 256;

  const int tid = threadIdx.x;
  const int lane = tid & 63, q = tid >> 6;   // q in 0..7
  const int h = blockIdx.x, b = blockIdx.y;

  // stage + f32->f16 channel-pair pack (registers -> cvt_pkrtz -> ds_write)
  const size_t gb = ((size_t)b * 32 * 128 + h) * 256;
  #pragma unroll
  for (int s = 0; s < 2; ++s) {
    int task = s * 512 + tid;           // 0..1023
    int cp = task >> 6, w4 = (task & 63) * 4;
    const float* la = lf + gb + (size_t)(2 * cp) * 32768 + w4;
    const float* ra = rf + gb + (size_t)(2 * cp) * 32768 + w4;
    f32x4 va = *reinterpret_cast<const f32x4*>(la);
    f32x4 vb = *reinterpret_cast<const f32x4*>(la + 32768);
    f32x4 wa = *reinterpret_cast<const f32x4*>(ra);
    f32x4 wb = *reinterpret_cast<const f32x4*>(ra + 32768);
    u32x4 lo, ro;
    #pragma unroll
    for (int e = 0; e < 4; ++e) {
      lo[e] = pk2u(__builtin_amdgcn_cvt_pkrtz(va[e], vb[e]));
      ro[e] = pk2u(__builtin_amdgcn_cvt_pkrtz(wa[e], wb[e]));
    }
    *reinterpret_cast<u32x4*>(&lfp[cp * 256 + w4]) = lo;
    *reinterpret_cast<u32x4*>(&rfp[cp * 272 + 16 + w4]) = ro;
  }
  __syncthreads();

  const int w0 = lane * 4;
  u16* orow = cost + ((size_t)(b * 128 + h)) * 49152 + w0 * 16;
  const h2 ones = (h2){(_Float16)1.f, (_Float16)1.f};

  #pragma unroll 1
  for (int t = 0; t < 3; ++t) {
    const int dblk = t * 8 + q;    // wave-uniform, 0..23
    const int d0 = dblk * 8;
    float acc[8][4];
    #pragma unroll
    for (int d = 0; d < 8; ++d)
      #pragma unroll
      for (int j = 0; j < 4; ++j) acc[d][j] = 0.f;

    // win[i] = rf-pair[w0 - d0 - 8 + i]; negative offsets land in lfp
    // (garbage, masked at store). Alignment: 16B (w0%4==0, d0%8==0).
    const u32* wrow = rfp + 16 + w0 - d0 - 8;
    const u32* lrow = lfp + w0;

    #pragma unroll 2
    for (int cp = 0; cp < 16; ++cp) {
      u32x4 lv = *reinterpret_cast<const u32x4*>(lrow + cp * 256);
      u32x4 a0 = *reinterpret_cast<const u32x4*>(wrow + cp * 272);
      u32x4 a1 = *reinterpret_cast<const u32x4*>(wrow + cp * 272 + 4);
      u32x4 a2 = *reinterpret_cast<const u32x4*>(wrow + cp * 272 + 8);
      u32 win[12];
      #pragma unroll
      for (int e = 0; e < 4; ++e) { win[e] = a0[e]; win[4 + e] = a1[e]; win[8 + e] = a2[e]; }
      #pragma unroll
      for (int d = 0; d < 8; ++d)
        #pragma unroll
        for (int j = 0; j < 4; ++j) {
          h2 diff = u2h2(lv[j]) - u2h2(win[j - d + 8]);
          u32 ad = h22u(diff) & 0x7FFF7FFFu;
          acc[d][j] = __builtin_amdgcn_fdot2(u2h2(ad), ones, acc[d][j], false);
        }
    }

    const int cg = dblk >> 1, dc0 = (dblk & 1) * 8;
    #pragma unroll
    for (int j = 0; j < 4; ++j) {
      u16x8 pk;
      #pragma unroll
      for (int d = 0; d < 8; ++d) {
        float v = acc[d][j] * (1.f / 32.f);
        pk[d] = (w0 + j >= d0 + d) ? f2h(v) : (u16)0;
      }
      *reinterpret_cast<u16x8*>(orow + cg * 4096 + j * 16 + dc0) = pk;
    }
  }
}

// ---------------- MFMA implicit-GEMM 3x3 conv ----------------
template<int OC>
__global__ __launch_bounds__(256) void cv_convm(
    const u16* __restrict__ act, const u16* __restrict__ wre,
    const float* __restrict__ bias, u16* __restrict__ yout,
    float* __restrict__ ps, float* __restrict__ pq, int NCG)
{
  constexpr int NF = OC / 16;
  constexpr int NWCH = (5 * OC * 32 * 2) / 1024;

  __shared__ __align__(16) u16 at[4 * 258 * 16];
  __shared__ __align__(16) u16 wl[5 * 64 * 32];
  __shared__ float reds[4][64];
  __shared__ float redq[4][64];

  const int tid = threadIdx.x;
  const int rp = blockIdx.x, b = blockIdx.y;
  const int h0 = rp * 2;
  const int q = tid >> 6, lane = tid & 63;
  const int lanelo = lane & 15, lanehi = lane >> 4;
  const int selB = lane >> 5;
  const int dcb = (lanehi & 1) * 8;
  const int r = q >> 1, hf = q & 1;
  const int wbase = hf * 128 + lanelo;

  if (tid < 128) {
    int tr = tid >> 5, side = (tid >> 4) & 1, dc = tid & 15;
    at[(tr * 258 + side * 257) * 16 + dc] = 0;
  }
  if (h0 == 0)   for (int i = tid; i < 258 * 16; i += 256) at[i] = 0;
  if (h0 == 126) for (int i = tid; i < 258 * 16; i += 256) at[3 * 258 * 16 + i] = 0;

  f32x4 acc[8][NF];
  #pragma unroll
  for (int mf = 0; mf < 8; ++mf)
    #pragma unroll
    for (int nf = 0; nf < NF; ++nf)
      acc[mf][nf] = (f32x4){0.f, 0.f, 0.f, 0.f};

  const int hsrc = h0 - 1 + q;
  const bool rowok = (hsrc >= 0) && (hsrc < 128);

  #pragma unroll 1
  for (int cg = 0; cg < NCG; ++cg) {
    if (rowok) {
      const u16* src = act + ((size_t)((b * 128 + hsrc) * NCG + cg)) * 4096;
      u16* dst = &at[(q * 258 + 1) * 16];
      #pragma unroll
      for (int i = 0; i < 8; ++i)
        gl_lds16(src + i * 512 + lane * 8, dst + i * 512);
    }
    {
      const u16* wsrc = wre + (size_t)cg * (5 * OC * 32);
      for (int ch = q; ch < NWCH; ch += 4)
        gl_lds16(wsrc + ch * 512 + lane * 8, &wl[ch * 512]);
    }
    __syncthreads();

    #pragma unroll
    for (int s = 0; s < 5; ++s) {
      const int tA = 2 * s, tB = (2 * s + 1 < 9) ? (2 * s + 1) : 8;
      const int khA = tA / 3, kwA = tA % 3;
      const int khB = tB / 3, kwB = tB % 3;
      const int kh = selB ? khB : khA;
      const int kw = selB ? kwB : kwA;
      h8 bfr[NF];
      #pragma unroll
      for (int nf = 0; nf < NF; ++nf)
        bfr[nf] = *reinterpret_cast<const h8*>(&wl[(s * OC + nf * 16 + lanelo) * 32 + lanehi * 8]);
      const int abase = ((r + kh) * 258 + wbase + kw) * 16 + dcb;
      #pragma unroll
      for (int mf = 0; mf < 8; ++mf) {
        h8 a = *reinterpret_cast<const h8*>(&at[abase + mf * 256]);
        #pragma unroll
        for (int nf = 0; nf < NF; ++nf)
          acc[mf][nf] = __builtin_amdgcn_mfma_f32_16x16x32_f16(a, bfr[nf], acc[mf][nf], 0, 0, 0);
      }
    }
    __syncthreads();
  }

  #pragma unroll
  for (int nf = 0; nf < NF; ++nf) {
    float bv = bias[nf * 16 + lanelo];
    #pragma unroll
    for (int mf = 0; mf < 8; ++mf)
      #pragma unroll
      for (int e = 0; e < 4; ++e)
        acc[mf][nf][e] += bv;
  }

  float s_[NF], qq[NF];
  #pragma unroll
  for (int nf = 0; nf < NF; ++nf) {
    s_[nf] = 0.f; qq[nf] = 0.f;
    #pragma unroll
    for (int mf = 0; mf < 8; ++mf)
      #pragma unroll
      for (int e = 0; e < 4; ++e) {
        float v = acc[mf][nf][e];
        s_[nf] += v; qq[nf] += v * v;
      }
  }
  #pragma unroll
  for (int nf = 0; nf < NF; ++nf) {
    s_[nf] += __shfl_xor(s_[nf], 16, 64);
    s_[nf] += __shfl_xor(s_[nf], 32, 64);
    qq[nf] += __shfl_xor(qq[nf], 16, 64);
    qq[nf] += __shfl_xor(qq[nf], 32, 64);
  }
  if (lanehi == 0) {
    #pragma unroll
    for (int nf = 0; nf < NF; ++nf) {
      reds[q][nf * 16 + lanelo] = s_[nf];
      redq[q][nf * 16 + lanelo] = qq[nf];
    }
  }
  __syncthreads();
  if (tid < OC) {
    int bid = b * 64 + rp;
    ps[bid * OC + tid] = reds[0][tid] + reds[1][tid] + reds[2][tid] + reds[3][tid];
    pq[bid * OC + tid] = redq[0][tid] + redq[1][tid] + redq[2][tid] + redq[3][tid];
  }

  u16* eb = at;
  #pragma unroll
  for (int nf = 0; nf < NF; ++nf) {
    __syncthreads();
    #pragma unroll
    for (int mf = 0; mf < 8; ++mf)
      #pragma unroll
      for (int e = 0; e < 4; ++e) {
        int px = r * 256 + hf * 128 + mf * 16 + lanehi * 4 + e;
        eb[px * 16 + lanelo] = f2h(acc[mf][nf][e]);
      }
    __syncthreads();
    #pragma unroll
    for (int j = 0; j < 4; ++j) {
      int c = j * 256 + tid;
      int row = c >> 9, off = (c & 511) * 8;
      u16x8 v = *reinterpret_cast<const u16x8*>(&eb[c * 8]);
      *reinterpret_cast<u16x8*>(
          yout + ((size_t)((b * 128 + h0 + row) * NF + nf)) * 4096 + off) = v;
    }
  }
}

// ---------------- finalize BN stats ----------------
__global__ void cv_fin1(const float* __restrict__ p1s, const float* __restrict__ p1q,
                        const float* __restrict__ g, const float* __restrict__ be,
                        float* __restrict__ bn1)
{
  int o = threadIdx.x;
  if (o >= 64) return;
  float s = 0.f, q = 0.f;
  #pragma unroll 4
  for (int k = 0; k < 512; ++k) { s += p1s[k * 64 + o]; q += p1q[k * 64 + o]; }
  float inv = 1.f / 262144.f;
  float mean = s * inv;
  float var = q * inv - mean * mean;
  float a = g[o] * rsqrtf(var + 1e-5f);
  bn1[o] = a;
  bn1[64 + o] = be[o] - mean * a;
}

__global__ void cv_fin2(const float* __restrict__ p2s, const float* __restrict__ p2q,
                        const float* __restrict__ g, const float* __restrict__ be,
                        float* __restrict__ bn2)
{
  int o = threadIdx.x;
  if (o >= 32) return;
  float s = 0.f, q = 0.f;
  #pragma unroll 4
  for (int k = 0; k < 512; ++k) { s += p2s[k * 32 + o]; q += p2q[k * 32 + o]; }
  float inv = 1.f / 262144.f;
  float mean = s * inv;
  float var = q * inv - mean * mean;
  float a = g[o] * rsqrtf(var + 1e-5f);
  bn2[o] = a;
  bn2[32 + o] = be[o] - mean * a;
}

// ---------------- y1 <- relu(bn1(y1)) in place ----------------
__global__ __launch_bounds__(256) void cv_bnrelu1(u16* __restrict__ y1,
                                                  const float* __restrict__ bn1)
{
  size_t i = ((size_t)blockIdx.x * 256 + threadIdx.x) * 8;
  int dc0 = (int)(i & 15);
  int cg = (int)((i >> 12) & 3);
  int o0 = cg * 16 + dc0;
  f32x4 a0 = *reinterpret_cast<const f32x4*>(&bn1[o0]);
  f32x4 a1 = *reinterpret_cast<const f32x4*>(&bn1[o0 + 4]);
  f32x4 s0 = *reinterpret_cast<const f32x4*>(&bn1[64 + o0]);
  f32x4 s1 = *reinterpret_cast<const f32x4*>(&bn1[64 + o0 + 4]);
  u16x8 v = *reinterpret_cast<const u16x8*>(&y1[i]);
  u16x8 outv;
  #pragma unroll
  for (int j = 0; j < 8; ++j) {
    float aj = (j < 4) ? a0[j] : a1[j - 4];
    float sj = (j < 4) ? s0[j] : s1[j - 4];
    float f = fmaxf(fmaf(h2f(v[j]), aj, sj), 0.f);
    outv[j] = f2h(f);
  }
  *reinterpret_cast<u16x8*>(&y1[i]) = outv;
}

// ---------------- deconv ----------------
__global__ __launch_bounds__(256) void cv_deconv(
    const u16* __restrict__ y2, const float* __restrict__ bn2,
    const float* __restrict__ wd, const float* __restrict__ db,
    float* __restrict__ out)
{
  const int tid = threadIdx.x;
  const int blk = blockIdx.x;
  const int b = blk >> 9;
  const int oh = (blk >> 1) & 255;
  const int ow = (blk & 1) * 256 + tid;
  float acc = db[0];
  const int qp = (oh + 1) & 1;
  const int rp = (ow + 1) & 1;
  #pragma unroll
  for (int t = 0; t < 2; ++t) {
    int kh = qp + 2 * t;
    int ih = (oh + 1 - kh) >> 1;
    if (ih < 0 || ih >= 128) continue;
    #pragma unroll
    for (int u = 0; u < 2; ++u) {
      int kw = rp + 2 * u;
      int iw = (ow + 1 - kw) >> 1;
      if (iw < 0 || iw >= 256) continue;
      const u16* base = y2 + (size_t)(b * 128 + ih) * 8192 + iw * 16;
      #pragma unroll
      for (int c = 0; c < 32; ++c) {
        float v = h2f(base[(c >> 4) * 4096 + (c & 15)]);
        float x = fmaxf(fmaf(v, bn2[c], bn2[32 + c]), 0.f);
        acc = fmaf(x, wd[c * 16 + kh * 4 + kw], acc);
      }
    }
  }
  out[(size_t)(b * 256 + oh) * 512 + ow] = acc;
}

// ---------------- launcher ----------------
extern "C" void kernel_launch(void* const* d_in, const int* in_sizes, int n_in,
                              void* d_out, int out_size, void* d_ws, size_t ws_size,
                              hipStream_t stream)
{
  const float* lf  = (const float*)d_in[0];
  const float* rf  = (const float*)d_in[1];
  const float* w1  = (const float*)d_in[2];
  const float* b1  = (const float*)d_in[3];
  const float* g1  = (const float*)d_in[4];
  const float* be1 = (const float*)d_in[5];
  const float* w2  = (const float*)d_in[6];
  const float* b2  = (const float*)d_in[7];
  const float* g2  = (const float*)d_in[8];
  const float* be2 = (const float*)d_in[9];
  const float* wdc = (const float*)d_in[10];
  const float* dbc = (const float*)d_in[11];
  float* out = (float*)d_out;

  char* ws = (char*)d_ws;
  u16* cost  = (u16*)(ws + OFF_COST);
  u16* y1    = (u16*)(ws + OFF_Y1);
  u16* y2    = (u16*)(ws + OFF_Y2);
  u16* w1s   = (u16*)(ws + OFF_W1S);
  u16* w2s   = (u16*)(ws + OFF_W2S);
  float* p1s = (float*)(ws + OFF_P1S);
  float* p1q = (float*)(ws + OFF_P1Q);
  float* p2s = (float*)(ws + OFF_P2S);
  float* p2q = (float*)(ws + OFF_P2Q);
  float* bn1 = (float*)(ws + OFF_BN1);
  float* bn2 = (float*)(ws + OFF_BN2);

  cv_prep<<<dim3(480), dim3(256), 0, stream>>>(w1, w2, w1s, w2s);
  cv_cost<<<dim3(128, 8), dim3(512), 0, stream>>>(lf, rf, cost);
  cv_convm<64><<<dim3(64, 8), dim3(256), 0, stream>>>(cost, w1s, b1, y1, p1s, p1q, 12);
  cv_fin1<<<dim3(1), dim3(64), 0, stream>>>(p1s, p1q, g1, be1, bn1);
  cv_bnrelu1<<<dim3(8192), dim3(256), 0, stream>>>(y1, bn1);
  cv_convm<32><<<dim3(64, 8), dim3(256), 0, stream>>>(y1, w2s, b2, y2, p2s, p2q, 4);
  cv_fin2<<<dim3(1), dim3(64), 0, stream>>>(p2s, p2q, g2, be2, bn2);
  cv_deconv<<<dim3(4096), dim3(256), 0, stream>>>(y2, bn2, wdc, dbc, out);
}